// Round 12
// baseline (405.294 us; speedup 1.0000x reference)
//
#include <hip/hip_runtime.h>
#include <cstdint>
#include <cstddef>

#define T_LEN 4096
#define C_DIM 256
#define B_DIM 8
#define K_TOP 4

typedef __attribute__((ext_vector_type(8))) short bf16x8;
typedef __attribute__((ext_vector_type(4))) float f32x4;

// tanh-form GELU: x * sigmoid(1.59577x + 0.0713548x^3); |delta| vs exact
// erf-GELU ~2.5e-4, below the bf16 quant noise already in the buffers.
__device__ __forceinline__ float gelu_fast(float x) {
    float x2 = x * x;
    float a = x * fmaf(0.071354816f, x2, 1.595769122f);
    float e = __expf(-a);
    return __fdividef(x, 1.0f + e);
}

__device__ __forceinline__ unsigned short f2bf(float f) {
    uint32_t u = __float_as_uint(f);
    uint32_t r = (u + 0x7fffu + ((u >> 16) & 1u)) >> 16;
    return (unsigned short)r;
}

typedef __attribute__((address_space(3))) uint32_t lds_u32_t;
typedef __attribute__((address_space(1))) const uint32_t gbl_u32_t;

__device__ __forceinline__ void lds_load16(const void* g, void* l) {
    __builtin_amdgcn_global_load_lds((gbl_u32_t*)g, (lds_u32_t*)l, 16, 0, 0);
}

// raw barriers with explicit (counted) waits
#define BAR_VM0()                                                      \
    do {                                                               \
        asm volatile("s_waitcnt vmcnt(0) lgkmcnt(0)" ::: "memory");    \
        __builtin_amdgcn_s_barrier();                                  \
        __builtin_amdgcn_sched_barrier(0);                             \
    } while (0)
#define BAR_VM4()                                                      \
    do {                                                               \
        asm volatile("s_waitcnt vmcnt(4) lgkmcnt(0)" ::: "memory");    \
        __builtin_amdgcn_s_barrier();                                  \
        __builtin_amdgcn_sched_barrier(0);                             \
    } while (0)
#define BAR_LGKM()                                                     \
    do {                                                               \
        asm volatile("s_waitcnt lgkmcnt(0)" ::: "memory");             \
        __builtin_amdgcn_s_barrier();                                  \
        __builtin_amdgcn_sched_barrier(0);                             \
    } while (0)

// padded LDS index for FFT: +1 float per 32
#define FPAD(i) ((i) + ((i) >> 5))

// ------------------------------------------------------------------
// xbf = bf16(x) (out is produced by the FF epilogue), plus zero page
// ------------------------------------------------------------------
__global__ __launch_bounds__(256) void cvt_x_kernel(const float4* __restrict__ x,
                                                    ushort4* __restrict__ xbf,
                                                    unsigned short* __restrict__ zbuf) {
    size_t i = (size_t)blockIdx.x * 256 + threadIdx.x;
    float4 v = x[i];
    ushort4 o;
    o.x = f2bf(v.x); o.y = f2bf(v.y); o.z = f2bf(v.z); o.w = f2bf(v.w);
    xbf[i] = o;
    if (blockIdx.x == 0 && threadIdx.x < 256) zbuf[threadIdx.x] = 0;
}

// ------------------------------------------------------------------
// fp32 [R][C] -> bf16 transposed [C][R]   (conv weights)
// ------------------------------------------------------------------
__global__ __launch_bounds__(256) void transpose_cvt_kernel(const float* __restrict__ src,
                                                            unsigned short* __restrict__ dst,
                                                            int R, int C) {
    __shared__ float t[32][33];
    const int c0 = blockIdx.x * 32, r0 = blockIdx.y * 32;
    const int lx = threadIdx.x & 31, ly = threadIdx.x >> 5;
    for (int rr = ly; rr < 32; rr += 8) {
        int r = r0 + rr, c = c0 + lx;
        t[rr][lx] = (r < R && c < C) ? src[(size_t)r * C + c] : 0.0f;
    }
    __syncthreads();
    for (int rr = ly; rr < 32; rr += 8) {
        int c = c0 + rr, r = r0 + lx;
        if (r < R && c < C) dst[(size_t)c * R + r] = f2bf(t[lx][rr]);
    }
}

// ------------------------------------------------------------------
// fp32 src[K][N] -> bf16 MFMA fragment tiles (A- and B-compatible).
// ------------------------------------------------------------------
__global__ __launch_bounds__(256) void repack_frag_kernel(const float* __restrict__ src,
                                                          unsigned short* __restrict__ dst,
                                                          int K, int N) {
    int idx = blockIdx.x * 256 + threadIdx.x;  // (tile, lane)
    int total = (N >> 4) * (K >> 5) * 64;
    if (idx >= total) return;
    int lane = idx & 63, tile = idx >> 6;
    int ktiles = K >> 5;
    int tile_n = tile / ktiles, tile_k = tile % ktiles;
    int col = tile_n * 16 + (lane & 15);
    int k0 = tile_k * 32 + (lane >> 4) * 8;
    __align__(16) unsigned short v[8];
#pragma unroll
    for (int j = 0; j < 8; j++) v[j] = f2bf(src[(size_t)(k0 + j) * N + col]);
    *(uint4*)(dst + (size_t)idx * 8) = *(const uint4*)v;
}

// ------------------------------------------------------------------
// fp32 x[b][t][c] -> xT[b][c][t]
// ------------------------------------------------------------------
__global__ __launch_bounds__(256) void transpose_x_kernel(const float* __restrict__ x,
                                                          float* __restrict__ xT) {
    __shared__ float tile[32][33];
    const int b = blockIdx.z;
    const int t0 = blockIdx.x * 32, c0 = blockIdx.y * 32;
    const int lx = threadIdx.x & 31, ly = threadIdx.x >> 5;
    const float* xp = x + (size_t)b * T_LEN * C_DIM;
    float* op = xT + (size_t)b * C_DIM * T_LEN;
    for (int rr = ly; rr < 32; rr += 8)
        tile[rr][lx] = xp[(size_t)(t0 + rr) * C_DIM + c0 + lx];
    __syncthreads();
    for (int rr = ly; rr < 32; rr += 8)
        op[(size_t)(c0 + rr) * T_LEN + t0 + lx] = tile[lx][rr];
}

// ------------------------------------------------------------------
// Per-(b,c) 4096-pt FFT, fused radix-2 stage-pairs, pad-32 LDS.
// ------------------------------------------------------------------
__global__ __launch_bounds__(256) void fft_mag_kernel(const float* __restrict__ src,
                                                      float* __restrict__ mags,
                                                      int transposed) {
    const int bx = blockIdx.x;
    const int b = bx >> 8;
    const int c = bx & 255;
    const int tid = threadIdx.x;

    __shared__ __align__(16) float re[4224];
    __shared__ __align__(16) float im[4224];
    __shared__ __align__(16) float twr[2048];
    __shared__ __align__(16) float twi[2048];

    for (int u = tid; u < 2048; u += 256) {
        float ang = -6.283185307179586f * (float)u / 4096.0f;
        float s, co;
        sincosf(ang, &s, &co);
        twr[u] = co;
        twi[u] = s;
    }
    for (int i = tid; i < 4224; i += 256) im[i] = 0.0f;

    if (transposed) {
        const float4* row = (const float4*)(src + ((size_t)(b * C_DIM + c)) * T_LEN);
        for (int e4 = tid; e4 < 1024; e4 += 256) {
            float4 v = row[e4];
            int e = e4 * 4;
            re[FPAD((int)(__brev((unsigned)(e + 0)) >> 20))] = v.x;
            re[FPAD((int)(__brev((unsigned)(e + 1)) >> 20))] = v.y;
            re[FPAD((int)(__brev((unsigned)(e + 2)) >> 20))] = v.z;
            re[FPAD((int)(__brev((unsigned)(e + 3)) >> 20))] = v.w;
        }
    } else {
        const float* xp = src + (size_t)b * T_LEN * C_DIM + c;
        for (int e = tid; e < 4096; e += 256) {
            int r = (int)(__brev((unsigned)e) >> 20);
            re[FPAD(r)] = xp[(size_t)e * C_DIM];
        }
    }
    __syncthreads();

#pragma unroll
    for (int sp = 0; sp < 6; sp++) {
        const int h = 1 << (2 * sp);
        const int t1s = 11 - 2 * sp;
        const int t2s = 10 - 2 * sp;
        for (int j = tid; j < 1024; j += 256) {
            int p = j & (h - 1);
            int G = j >> (2 * sp);
            int base = G * 4 * h + p;
            int iA = FPAD(base), iB = FPAD(base + h);
            int iC = FPAD(base + 2 * h), iD = FPAD(base + 3 * h);
            float w1r = twr[p << t1s], w1i = twi[p << t1s];
            float w2r = twr[p << t2s], w2i = twi[p << t2s];
            float Ar = re[iA], Ai = im[iA], Br = re[iB], Bi = im[iB];
            float Cr = re[iC], Ci = im[iC], Dr = re[iD], Di = im[iD];
            float tBr = w1r * Br - w1i * Bi, tBi = w1r * Bi + w1i * Br;
            float tDr = w1r * Dr - w1i * Di, tDi = w1r * Di + w1i * Dr;
            float A1r = Ar + tBr, A1i = Ai + tBi;
            float B1r = Ar - tBr, B1i = Ai - tBi;
            float C1r = Cr + tDr, C1i = Ci + tDi;
            float D1r = Cr - tDr, D1i = Ci - tDi;
            float tCr = w2r * C1r - w2i * C1i, tCi = w2r * C1i + w2i * C1r;
            float uDr = w2r * D1r - w2i * D1i, uDi = w2r * D1i + w2i * D1r;
            float vDr = uDi, vDi = -uDr;
            re[iA] = A1r + tCr; im[iA] = A1i + tCi;
            re[iC] = A1r - tCr; im[iC] = A1i - tCi;
            re[iB] = B1r + vDr; im[iB] = B1i + vDi;
            re[iD] = B1r - vDr; im[iD] = B1i - vDi;
        }
        __syncthreads();
    }

    float* mp = mags + ((size_t)(b * C_DIM + c)) * 2048;
    for (int u = tid; u < 2048; u += 256) {
        int f = FPAD(u + 1);
        mp[u] = sqrtf(re[f] * re[f] + im[f] * im[f]);
    }
}

// ------------------------------------------------------------------
// partial[b][cc][u] = sum over 32 channels of mags
// ------------------------------------------------------------------
__global__ __launch_bounds__(256) void reduce_amps_kernel(const float* __restrict__ mags,
                                                          float* __restrict__ partial) {
    const int b = blockIdx.z, cc = blockIdx.y;
    const int u = blockIdx.x * 256 + threadIdx.x;
    const float* mp = mags + ((size_t)b * C_DIM + cc * 32) * 2048 + u;
    float s = 0.0f;
    for (int c = 0; c < 32; c++) s += mp[(size_t)c * 2048];
    partial[((size_t)b * 8 + cc) * 2048 + u] = s;
}

// ------------------------------------------------------------------
// Per-batch top-4 (value desc, ties -> lower index), periods, softmax
// ------------------------------------------------------------------
__global__ __launch_bounds__(256) void topk_kernel(const float* __restrict__ partial,
                                                   int* __restrict__ meta_p,
                                                   float* __restrict__ meta_w) {
    const int b = blockIdx.x;
    const int tid = threadIdx.x;
    __shared__ float v[2048];
    __shared__ float rv[256];
    __shared__ int ri[256];
    __shared__ float topv[K_TOP];
    __shared__ int topi[K_TOP];

    for (int u = tid; u < 2048; u += 256) {
        float s = 0.0f;
        for (int cc = 0; cc < 8; cc++) s += partial[((size_t)b * 8 + cc) * 2048 + u];
        v[u] = s * (1.0f / (float)C_DIM);
    }

    for (int k = 0; k < K_TOP; k++) {
        __syncthreads();
        float bv = -1e30f;
        int bi = 2048;
        for (int u = tid; u < 2048; u += 256) {
            float val = v[u];
            if (val > bv) { bv = val; bi = u; }
        }
        rv[tid] = bv;
        ri[tid] = bi;
        __syncthreads();
        for (int s = 128; s > 0; s >>= 1) {
            if (tid < s) {
                float ov = rv[tid + s];
                int oi = ri[tid + s];
                if (ov > rv[tid] || (ov == rv[tid] && oi < ri[tid])) {
                    rv[tid] = ov;
                    ri[tid] = oi;
                }
            }
            __syncthreads();
        }
        if (tid == 0) {
            topv[k] = rv[0];
            topi[k] = ri[0];
            v[ri[0]] = -1e30f;
        }
    }
    __syncthreads();
    if (tid == 0) {
        float mx = topv[0];
        for (int k = 1; k < K_TOP; k++) mx = fmaxf(mx, topv[k]);
        float e[K_TOP], se = 0.0f;
        for (int k = 0; k < K_TOP; k++) { e[k] = expf(topv[k] - mx); se += e[k]; }
        for (int k = 0; k < K_TOP; k++) {
            int idx = topi[k];
            int d = (idx >= 1) ? idx : 1;
            int p = T_LEN / d;
            if (p < 1) p = 1;
            meta_p[b * K_TOP + k] = p;
            meta_w[b * K_TOP + k] = e[k] / se;
        }
    }
}

// ------------------------------------------------------------------
// Conv as MFMA GEMM v4: 256x256 block tile, 8 waves (512 thr) in a
// 2(M)x4(N) grid, wave-tile 128x64 (acc[8][4], 128 AGPR).  Cuts LDS
// read bytes/FLOP 31->23 (A re-read 4x->2x... B 2x->1x per row pair)
// and doubles MFMA work per barrier.  3-buffer pipeline, stage s+2
// while computing s, counted vmcnt(4) barriers (4 stage-loads/thread/
// step).  Round-9 zero-conflict swizzle key (row>>1)&3 on both sides.
// LDS 96 KB -> 1 block/CU (8 waves); grid 512 = 2 passes.
// ------------------------------------------------------------------
__global__ __launch_bounds__(512) void conv_mfma_kernel(const unsigned short* __restrict__ xbf,
                                                        const unsigned short* __restrict__ WcT,
                                                        const float* __restrict__ bc,
                                                        const int* __restrict__ meta_p,
                                                        const unsigned short* __restrict__ zbuf,
                                                        unsigned short* __restrict__ convbufs,
                                                        size_t conv_stride, int koff) {
    const int b = blockIdx.y;
    const int kz = blockIdx.z;
    const int n = meta_p[b * K_TOP + koff + kz];
    const int row0 = blockIdx.x * 256;
    const int tid = threadIdx.x, w = tid >> 6, lane = tid & 63;
    const int wm = w >> 2, wn = w & 3;  // wave tile: rows [wm*128,+128), cols [wn*64,+64)

    __shared__ __align__(16) unsigned short Al[3][256 * 32];  // 3 x 16 KB
    __shared__ __align__(16) unsigned short Bl[3][256 * 32];  // 3 x 16 KB

    // staging: thread owns A rows {tid>>2, (tid>>2)+128} and B (=WcT) rows
    // {tid>>2, (tid>>2)+128}; chunk slot tid&3 within the 64B row.
    // swizzle chunk: sc = (tid&3) ^ ((row>>1)&3); row+128 leaves (row>>1)&3
    // unchanged, so sc is shared by both halves.
    const int ra = tid >> 2;
    const int swz = ((tid & 3) ^ ((ra >> 1) & 3)) * 8;  // element offset
    int ti[2], tj[2];
#pragma unroll
    for (int s01 = 0; s01 < 2; s01++) {
        int t = row0 + ra + s01 * 128;
        ti[s01] = t / n;
        tj[s01] = t - ti[s01] * n;
    }
    const unsigned short* xb = xbf + (size_t)b * T_LEN * C_DIM;
    const unsigned short* baseB0 = WcT + (size_t)ra * 2304 + swz;
    const unsigned short* baseB1 = WcT + (size_t)(ra + 128) * 2304 + swz;
    const unsigned short* baseA0;
    const unsigned short* baseA1;

    auto computeA = [&](int q, int s01) -> const unsigned short* {
        int di = q / 3 - 1, dj = q % 3 - 1;
        int ii = ti[s01] + di, jj = tj[s01] + dj;
        int tp = ii * n + jj;
        bool ok = (jj >= 0) && (jj < n) && (ii >= 0) && (tp < T_LEN);
        return ok ? (xb + (size_t)tp * C_DIM + swz) : (zbuf + swz);
    };

    f32x4 acc[8][4];
#pragma unroll
    for (int m = 0; m < 8; m++)
#pragma unroll
        for (int nn = 0; nn < 4; nn++) acc[m][nn] = (f32x4){0.f, 0.f, 0.f, 0.f};

    // prologue: stage K-steps 0 and 1 (q = 0 for both)
    baseA0 = computeA(0, 0);
    baseA1 = computeA(0, 1);
#pragma unroll
    for (int t = 0; t < 2; t++) {
        lds_load16(baseA0 + t * 32, &Al[t][tid * 8]);
        lds_load16(baseA1 + t * 32, &Al[t][(tid + 512) * 8]);
        lds_load16(baseB0 + t * 32, &Bl[t][tid * 8]);
        lds_load16(baseB1 + t * 32, &Bl[t][(tid + 512) * 8]);
    }

    int cur = 0, stb = 2;
    for (int s = 0; s < 72; s++) {
        // stage(s) complete; stage(s+1)'s 4 loads may stay in flight
        if (s < 71) BAR_VM4();
        else        BAR_VM0();

        const int t = s + 2;
        if (t < 72) {  // stage t into buf stb (readers drained at barrier)
            if ((t & 7) == 0) {
                int q = t >> 3;
                baseA0 = computeA(q, 0);
                baseA1 = computeA(q, 1);
            }
            const int ko = (t & 7) * 32;
            lds_load16(baseA0 + ko, &Al[stb][tid * 8]);
            lds_load16(baseA1 + ko, &Al[stb][(tid + 512) * 8]);
            lds_load16(baseB0 + (size_t)t * 32, &Bl[stb][tid * 8]);
            lds_load16(baseB1 + (size_t)t * 32, &Bl[stb][(tid + 512) * 8]);
        }

        bf16x8 bfr[4];
#pragma unroll
        for (int nn = 0; nn < 4; nn++) {
            int rowb = wn * 64 + nn * 16 + (lane & 15);
            bfr[nn] = *(const bf16x8*)((const char*)&Bl[cur][0] + rowb * 64 +
                                       (((lane >> 4) * 16) ^ (((rowb >> 1) & 3) << 4)));
        }
        __builtin_amdgcn_s_setprio(1);
#pragma unroll
        for (int m = 0; m < 8; m++) {
            int row = wm * 128 + m * 16 + (lane & 15);
            bf16x8 af = *(const bf16x8*)((const char*)&Al[cur][0] + row * 64 +
                                         (((lane >> 4) * 16) ^ (((row >> 1) & 3) << 4)));
#pragma unroll
            for (int nn = 0; nn < 4; nn++)
                acc[m][nn] = __builtin_amdgcn_mfma_f32_16x16x32_bf16(af, bfr[nn], acc[m][nn], 0, 0, 0);
        }
        __builtin_amdgcn_s_setprio(0);

        cur = (cur == 2) ? 0 : cur + 1;
        stb = (stb == 2) ? 0 : stb + 1;
    }

    unsigned short* ob = convbufs + (size_t)kz * conv_stride + (size_t)b * T_LEN * C_DIM;
#pragma unroll
    for (int nn = 0; nn < 4; nn++) {
        int col = wn * 64 + nn * 16 + (lane & 15);
        float bs = bc[col];
#pragma unroll
        for (int m = 0; m < 8; m++) {
            int rbase = row0 + wm * 128 + m * 16 + (lane >> 4) * 4;
#pragma unroll
            for (int r = 0; r < 4; r++) {
                float v = acc[m][nn][r] + bs;
                ob[(size_t)(rbase + r) * C_DIM + col] = f2bf(gelu_fast(v));
            }
        }
    }
}

// ------------------------------------------------------------------
// Fused FF v5 (round-11, unchanged):
// out = osrc + (sum_k wk*gelu(A_k@W1+b1)) @ W2 + b2scale*b2
// ------------------------------------------------------------------
template <int KCNT>
__global__ __launch_bounds__(256, 2) void fused_ff_kernel(
    const unsigned short* __restrict__ convbufs, size_t conv_stride,
    const unsigned short* __restrict__ W1frag,
    const unsigned short* __restrict__ W2frag,
    const float* __restrict__ b1,
    const float* __restrict__ b2,
    const float* __restrict__ meta_w,
    float* __restrict__ out,
    const float* __restrict__ osrc,   // x (init) or out (accumulate)
    float b2scale, int koff) {
    const int tid = threadIdx.x;
    const int wn = tid >> 6, lane = tid & 63;
    const int row0 = blockIdx.x * 32;
    const int b = row0 >> 12;

    __shared__ __align__(16) unsigned short Asw[KCNT * 32 * 256];   // KCNT*16 KB
    __shared__ __align__(16) unsigned short Hsw[2][32 * 128];       // 2 x 8 KB

    float wkv[KCNT];
#pragma unroll
    for (int kc = 0; kc < KCNT; kc++) wkv[kc] = meta_w[b * K_TOP + koff + kc];

    // ---- stage all KCNT A-strips once (linear LDS dest, inv-swizzled src) ----
    {
        const unsigned short* base = convbufs + (size_t)row0 * C_DIM;
#pragma unroll
        for (int u = 0; u < KCNT * 4; u++) {
            int ch = u * 256 + tid;      // 16B chunk id
            int rfull = ch >> 5;         // row in Asw (= kc*32 + trow)
            int kc = rfull >> 5;
            int trow = rfull & 31;
            int cole = ((ch & 31) * 8) ^ ((rfull & 7) << 3);
            lds_load16(base + (size_t)kc * conv_stride + (size_t)trow * 256 + cole,
                       (unsigned short*)Asw + (size_t)ch * 8);
        }
    }

    f32x4 acc2[2][4];
#pragma unroll
    for (int t2 = 0; t2 < 2; t2++)
#pragma unroll
        for (int nn = 0; nn < 4; nn++) acc2[t2][nn] = (f32x4){0.f, 0.f, 0.f, 0.f};

    BAR_VM0();  // Asw landed

    for (int cc = 0; cc < 8; cc++) {
        const int par = cc & 1;

        // ---- GEMM1 (swapped) over all k: acc1[kc][n2][t2] = H^T frags ----
        f32x4 acc1[KCNT][2][2];
#pragma unroll
        for (int kc = 0; kc < KCNT; kc++)
#pragma unroll
            for (int n2 = 0; n2 < 2; n2++)
#pragma unroll
                for (int t2 = 0; t2 < 2; t2++) acc1[kc][n2][t2] = (f32x4){0.f, 0.f, 0.f, 0.f};

        __builtin_amdgcn_s_setprio(1);
#pragma unroll
        for (int ks = 0; ks < 8; ks++) {
            bf16x8 w1f[2];
#pragma unroll
            for (int n2 = 0; n2 < 2; n2++) {
                int tile_n = cc * 8 + wn * 2 + n2;
                w1f[n2] = *(const bf16x8*)(W1frag + ((size_t)(tile_n * 8 + ks) * 64 + lane) * 8);
            }
            bf16x8 af[KCNT][2];
#pragma unroll
            for (int kc = 0; kc < KCNT; kc++)
#pragma unroll
                for (int t2 = 0; t2 < 2; t2++) {
                    int row = kc * 32 + t2 * 16 + (lane & 15);
                    af[kc][t2] = *(const bf16x8*)((const char*)Asw + row * 512 +
                                                  ((ks * 64 + (lane >> 4) * 16) ^ ((row & 7) << 4)));
                }
#pragma unroll
            for (int kc = 0; kc < KCNT; kc++)
#pragma unroll
                for (int n2 = 0; n2 < 2; n2++)
#pragma unroll
                    for (int t2 = 0; t2 < 2; t2++)
                        acc1[kc][n2][t2] = __builtin_amdgcn_mfma_f32_16x16x32_bf16(
                            w1f[n2], af[kc][t2], acc1[kc][n2][t2], 0, 0, 0);
        }
        __builtin_amdgcn_s_setprio(0);

        // ---- combine: Hsw[par][t][h] = sum_k wk*gelu(acc1 + b1) (bf16) ----
#pragma unroll
        for (int n2 = 0; n2 < 2; n2++) {
            const int hloc = wn * 32 + n2 * 16 + (lane >> 4) * 4;  // 4 consecutive h
            f32x4 bb = *(const f32x4*)(b1 + cc * 128 + hloc);
#pragma unroll
            for (int t2 = 0; t2 < 2; t2++) {
                float hc[4];
#pragma unroll
                for (int r = 0; r < 4; r++) {
                    float s = 0.0f;
#pragma unroll
                    for (int kc = 0; kc < KCNT; kc++)
                        s += wkv[kc] * gelu_fast(acc1[kc][n2][t2][r] + bb[r]);
                    hc[r] = s;
                }
                uint32_t lo, hi;
                asm("v_cvt_pk_bf16_f32 %0, %1, %2" : "=v"(lo) : "v"(hc[0]), "v"(hc[1]));
                asm("v_cvt_pk_bf16_f32 %0, %1, %2" : "=v"(hi) : "v"(hc[2]), "v"(hc[3]));
                uint2 pk;
                pk.x = lo;
                pk.y = hi;
                int t = t2 * 16 + (lane & 15);
                *(uint2*)((char*)&Hsw[par][0] + t * 256 +
                          ((hloc * 2) ^ ((t & 7) << 4))) = pk;
            }
        }
        BAR_LGKM();  // Hsw[par] visible; global prefetches stay in flight

        // ---- GEMM2 once per chunk: acc2 += Hcomb @ W2chunk ----
        __builtin_amdgcn_s_setprio(1);
#pragma unroll
        for (int ks2 = 0; ks2 < 4; ks2++) {
            bf16x8 af2[2], w2f[4];
#pragma unroll
            for (int t2 = 0; t2 < 2; t2++) {
                int row = t2 * 16 + (lane & 15);
                af2[t2] = *(const bf16x8*)((const char*)&Hsw[par][0] + row * 256 +
                                           ((ks2 * 64 + (lane >> 4) * 16) ^ ((row & 7) << 4)));
            }
#pragma unroll
            for (int nn = 0; nn < 4; nn++) {
                int tile_n = wn * 4 + nn;
                int tile_k = cc * 4 + ks2;
                w2f[nn] = *(const bf16x8*)(W2frag + ((size_t)(tile_n * 32 + tile_k) * 64 + lane) * 8);
            }
#pragma unroll
            for (int t2 = 0; t2 < 2; t2++)
#pragma unroll
                for (int nn = 0; nn < 4; nn++)
                    acc2[t2][nn] = __builtin_amdgcn_mfma_f32_16x16x32_bf16(af2[t2], w2f[nn],
                                                                           acc2[t2][nn], 0, 0, 0);
        }
        __builtin_amdgcn_s_setprio(0);
        // no barrier: next chunk writes Hsw[par^1], whose readers (GEMM2 at
        // cc-1) are ordered before the BAR_LGKM above.
    }

    // ---- epilogue: out = osrc + acc2 + b2scale*b2 ----
#pragma unroll
    for (int nn = 0; nn < 4; nn++) {
        int col = wn * 64 + nn * 16 + (lane & 15);
        float bb = b2scale * b2[col];
#pragma unroll
        for (int t2 = 0; t2 < 2; t2++) {
            int rbase = row0 + t2 * 16 + (lane >> 4) * 4;
#pragma unroll
            for (int r = 0; r < 4; r++) {
                size_t idx = (size_t)(rbase + r) * C_DIM + col;
                out[idx] = osrc[idx] + acc2[t2][nn][r] + bb;
            }
        }
    }
}

// ------------------------------------------------------------------
extern "C" void kernel_launch(void* const* d_in, const int* in_sizes, int n_in,
                              void* d_out, int out_size, void* d_ws, size_t ws_size,
                              hipStream_t stream) {
    const float* x  = (const float*)d_in[0];
    const float* Wc = (const float*)d_in[1];
    const float* bc = (const float*)d_in[2];
    const float* W1 = (const float*)d_in[3];
    const float* b1 = (const float*)d_in[4];
    const float* W2 = (const float*)d_in[5];
    const float* b2 = (const float*)d_in[6];
    float* out = (float*)d_out;

    const size_t CONV_ELEMS = (size_t)B_DIM * T_LEN * C_DIM;     // 8M
    const size_t CONV_BYTES = CONV_ELEMS * 2;                    // 16.78 MB
    const size_t MAGS_BYTES = (size_t)B_DIM * C_DIM * 2048 * 4;  // 16.78 MB
    const size_t XT_BYTES = (size_t)B_DIM * T_LEN * C_DIM * 4;   // 33.55 MB

    // ---- fixed carve ----
    uint8_t* ws = (uint8_t*)d_ws;
    size_t off = 0;
    auto alloc = [&](size_t bytes) {
        size_t o = off;
        off = (off + bytes + 255) & ~(size_t)255;
        return o;
    };
    float* partial = (float*)(ws + alloc((size_t)B_DIM * 8 * 2048 * 4));
    int* meta_p = (int*)(ws + alloc(B_DIM * K_TOP * 4));
    float* meta_w = (float*)(ws + alloc(B_DIM * K_TOP * 4));
    unsigned short* xbf = (unsigned short*)(ws + alloc((size_t)B_DIM * T_LEN * C_DIM * 2));
    unsigned short* WcT = (unsigned short*)(ws + alloc((size_t)256 * 2304 * 2));
    unsigned short* W1frag = (unsigned short*)(ws + alloc((size_t)256 * 1024 * 2));
    unsigned short* W2frag = (unsigned short*)(ws + alloc((size_t)1024 * 256 * 2));
    unsigned short* zbuf = (unsigned short*)(ws + alloc(512));

    // ---- tiered regionA ----
    size_t remaining = (ws_size > off) ? (ws_size - off) : 0;
    uint8_t* regionA = ws + off;
    int tier;  // 2=FULL(4 convbufs), 1=MID(1 convbuf + xT), 0=MIN
    if (remaining >= 4 * CONV_BYTES) tier = 2;
    else if (remaining >= MAGS_BYTES + XT_BYTES) tier = 1;
    else tier = 0;

    float* mags = (float*)regionA;  // FFT phase (dead before conv)
    float* xT = (float*)(regionA + ((tier == 2) ? CONV_BYTES : MAGS_BYTES));
    unsigned short* convbufs = (unsigned short*)regionA;
    const int use_xT = (tier >= 1);

    // 1. xbf = bf16(x) ; zero page  (out is produced by the FF epilogue)
    cvt_x_kernel<<<dim3((B_DIM * T_LEN * C_DIM / 4) / 256), 256, 0, stream>>>(
        (const float4*)x, (ushort4*)xbf, zbuf);

    // 2. weight prep
    transpose_cvt_kernel<<<dim3(256 / 32, 2304 / 32), 256, 0, stream>>>(Wc, WcT, 2304, 256);
    repack_frag_kernel<<<dim3(128), 256, 0, stream>>>(W1, W1frag, 256, 1024);
    repack_frag_kernel<<<dim3(128), 256, 0, stream>>>(W2, W2frag, 1024, 256);

    // 3. FFT magnitudes, reduce, top-4
    if (use_xT) {
        transpose_x_kernel<<<dim3(T_LEN / 32, C_DIM / 32, B_DIM), 256, 0, stream>>>(x, xT);
        fft_mag_kernel<<<dim3(B_DIM * C_DIM), 256, 0, stream>>>(xT, mags, 1);
    } else {
        fft_mag_kernel<<<dim3(B_DIM * C_DIM), 256, 0, stream>>>(x, mags, 0);
    }
    reduce_amps_kernel<<<dim3(2048 / 256, 8, B_DIM), 256, 0, stream>>>(mags, partial);
    topk_kernel<<<dim3(B_DIM), 256, 0, stream>>>(partial, meta_p, meta_w);

    // 4. conv (all k) then fused FF (combined over k)
    if (tier == 2) {
        conv_mfma_kernel<<<dim3(16, B_DIM, K_TOP), 512, 0, stream>>>(
            xbf, WcT, bc, meta_p, zbuf, convbufs, CONV_ELEMS, 0);
        fused_ff_kernel<4><<<dim3(B_DIM * T_LEN / 32), 256, 0, stream>>>(
            convbufs, CONV_ELEMS, W1frag, W2frag, b1, b2, meta_w, out, x, 1.0f, 0);
    } else {
        for (int k = 0; k < K_TOP; k++) {
            conv_mfma_kernel<<<dim3(16, B_DIM, 1), 512, 0, stream>>>(
                xbf, WcT, bc, meta_p, zbuf, convbufs, 0, k);
            fused_ff_kernel<1><<<dim3(B_DIM * T_LEN / 32), 256, 0, stream>>>(
                convbufs, 0, W1frag, W2frag, b1, b2, meta_w, out,
                (k == 0) ? x : out, (k == K_TOP - 1) ? 1.0f : 0.0f, k);
        }
    }
}

// Round 13
// 385.245 us; speedup vs baseline: 1.0520x; 1.0520x over previous
//
#include <hip/hip_runtime.h>
#include <cstdint>
#include <cstddef>

#define T_LEN 4096
#define C_DIM 256
#define B_DIM 8
#define K_TOP 4

typedef __attribute__((ext_vector_type(8))) short bf16x8;
typedef __attribute__((ext_vector_type(4))) float f32x4;

// tanh-form GELU: x * sigmoid(1.59577x + 0.0713548x^3); |delta| vs exact
// erf-GELU ~2.5e-4, below the bf16 quant noise already in the buffers.
__device__ __forceinline__ float gelu_fast(float x) {
    float x2 = x * x;
    float a = x * fmaf(0.071354816f, x2, 1.595769122f);
    float e = __expf(-a);
    return __fdividef(x, 1.0f + e);
}

__device__ __forceinline__ unsigned short f2bf(float f) {
    uint32_t u = __float_as_uint(f);
    uint32_t r = (u + 0x7fffu + ((u >> 16) & 1u)) >> 16;
    return (unsigned short)r;
}

__device__ __forceinline__ float bf2f(unsigned short v) {
    uint32_t u = ((uint32_t)v) << 16;
    return __uint_as_float(u);
}

typedef __attribute__((address_space(3))) uint32_t lds_u32_t;
typedef __attribute__((address_space(1))) const uint32_t gbl_u32_t;

__device__ __forceinline__ void lds_load16(const void* g, void* l) {
    __builtin_amdgcn_global_load_lds((gbl_u32_t*)g, (lds_u32_t*)l, 16, 0, 0);
}

// raw barriers with explicit (counted) waits
#define BAR_VM0()                                                      \
    do {                                                               \
        asm volatile("s_waitcnt vmcnt(0) lgkmcnt(0)" ::: "memory");    \
        __builtin_amdgcn_s_barrier();                                  \
        __builtin_amdgcn_sched_barrier(0);                             \
    } while (0)
#define BAR_VM3()                                                      \
    do {                                                               \
        asm volatile("s_waitcnt vmcnt(3) lgkmcnt(0)" ::: "memory");    \
        __builtin_amdgcn_s_barrier();                                  \
        __builtin_amdgcn_sched_barrier(0);                             \
    } while (0)
#define BAR_LGKM()                                                     \
    do {                                                               \
        asm volatile("s_waitcnt lgkmcnt(0)" ::: "memory");             \
        __builtin_amdgcn_s_barrier();                                  \
        __builtin_amdgcn_sched_barrier(0);                             \
    } while (0)

// padded LDS index for FFT: +1 float per 32
#define FPAD(i) ((i) + ((i) >> 5))

// ------------------------------------------------------------------
// Fallback (no-xT tier): xbf = bf16(x), plus zero page
// ------------------------------------------------------------------
__global__ __launch_bounds__(256) void cvt_x_kernel(const float4* __restrict__ x,
                                                    ushort4* __restrict__ xbf,
                                                    unsigned short* __restrict__ zbuf) {
    size_t i = (size_t)blockIdx.x * 256 + threadIdx.x;
    float4 v = x[i];
    ushort4 o;
    o.x = f2bf(v.x); o.y = f2bf(v.y); o.z = f2bf(v.z); o.w = f2bf(v.w);
    xbf[i] = o;
    if (blockIdx.x == 0 && threadIdx.x < 256) zbuf[threadIdx.x] = 0;
}

// ------------------------------------------------------------------
// Fused: one read of x produces xT[b][c][t] (fp32, for FFT) AND
// xbf[b][t][c] (bf16, for conv), plus the zero page.
// ------------------------------------------------------------------
__global__ __launch_bounds__(256) void transpose_cvtx_kernel(const float* __restrict__ x,
                                                             float* __restrict__ xT,
                                                             unsigned short* __restrict__ xbf,
                                                             unsigned short* __restrict__ zbuf) {
    __shared__ float tile[32][33];
    const int b = blockIdx.z;
    const int t0 = blockIdx.x * 32, c0 = blockIdx.y * 32;
    const int lx = threadIdx.x & 31, ly = threadIdx.x >> 5;
    const float* xp = x + (size_t)b * T_LEN * C_DIM;
    unsigned short* xbp = xbf + (size_t)b * T_LEN * C_DIM;
    float* op = xT + (size_t)b * C_DIM * T_LEN;
    for (int rr = ly; rr < 32; rr += 8) {
        float v = xp[(size_t)(t0 + rr) * C_DIM + c0 + lx];
        tile[rr][lx] = v;
        xbp[(size_t)(t0 + rr) * C_DIM + c0 + lx] = f2bf(v);
    }
    __syncthreads();
    for (int rr = ly; rr < 32; rr += 8)
        op[(size_t)(c0 + rr) * T_LEN + t0 + lx] = tile[lx][rr];
    if (blockIdx.x == 0 && blockIdx.y == 0 && blockIdx.z == 0)
        zbuf[threadIdx.x] = 0;
}

// ------------------------------------------------------------------
// fp32 [R][C] -> bf16 transposed [C][R]   (conv weights)
// ------------------------------------------------------------------
__global__ __launch_bounds__(256) void transpose_cvt_kernel(const float* __restrict__ src,
                                                            unsigned short* __restrict__ dst,
                                                            int R, int C) {
    __shared__ float t[32][33];
    const int c0 = blockIdx.x * 32, r0 = blockIdx.y * 32;
    const int lx = threadIdx.x & 31, ly = threadIdx.x >> 5;
    for (int rr = ly; rr < 32; rr += 8) {
        int r = r0 + rr, c = c0 + lx;
        t[rr][lx] = (r < R && c < C) ? src[(size_t)r * C + c] : 0.0f;
    }
    __syncthreads();
    for (int rr = ly; rr < 32; rr += 8) {
        int c = c0 + rr, r = r0 + lx;
        if (r < R && c < C) dst[(size_t)c * R + r] = f2bf(t[lx][rr]);
    }
}

// ------------------------------------------------------------------
// fp32 src[K][N] -> bf16 MFMA fragment tiles (A- and B-compatible).
// ------------------------------------------------------------------
__global__ __launch_bounds__(256) void repack_frag_kernel(const float* __restrict__ src,
                                                          unsigned short* __restrict__ dst,
                                                          int K, int N) {
    int idx = blockIdx.x * 256 + threadIdx.x;  // (tile, lane)
    int total = (N >> 4) * (K >> 5) * 64;
    if (idx >= total) return;
    int lane = idx & 63, tile = idx >> 6;
    int ktiles = K >> 5;
    int tile_n = tile / ktiles, tile_k = tile % ktiles;
    int col = tile_n * 16 + (lane & 15);
    int k0 = tile_k * 32 + (lane >> 4) * 8;
    __align__(16) unsigned short v[8];
#pragma unroll
    for (int j = 0; j < 8; j++) v[j] = f2bf(src[(size_t)(k0 + j) * N + col]);
    *(uint4*)(dst + (size_t)idx * 8) = *(const uint4*)v;
}

// ------------------------------------------------------------------
// Per-(b,c) 4096-pt FFT, fused radix-2 stage-pairs, pad-32 LDS.
// Writes |X_f| as bf16 (consumed only by a mean; 1.2e-4 relative
// noise after channel-mean vs ~1% top-k gaps -> 50-100x margin).
// ------------------------------------------------------------------
__global__ __launch_bounds__(256) void fft_mag_kernel(const float* __restrict__ src,
                                                      unsigned short* __restrict__ mags,
                                                      int transposed) {
    const int bx = blockIdx.x;
    const int b = bx >> 8;
    const int c = bx & 255;
    const int tid = threadIdx.x;

    __shared__ __align__(16) float re[4224];
    __shared__ __align__(16) float im[4224];
    __shared__ __align__(16) float twr[2048];
    __shared__ __align__(16) float twi[2048];

    for (int u = tid; u < 2048; u += 256) {
        float ang = -6.283185307179586f * (float)u / 4096.0f;
        float s, co;
        sincosf(ang, &s, &co);
        twr[u] = co;
        twi[u] = s;
    }
    for (int i = tid; i < 4224; i += 256) im[i] = 0.0f;

    if (transposed) {
        const float4* row = (const float4*)(src + ((size_t)(b * C_DIM + c)) * T_LEN);
        for (int e4 = tid; e4 < 1024; e4 += 256) {
            float4 v = row[e4];
            int e = e4 * 4;
            re[FPAD((int)(__brev((unsigned)(e + 0)) >> 20))] = v.x;
            re[FPAD((int)(__brev((unsigned)(e + 1)) >> 20))] = v.y;
            re[FPAD((int)(__brev((unsigned)(e + 2)) >> 20))] = v.z;
            re[FPAD((int)(__brev((unsigned)(e + 3)) >> 20))] = v.w;
        }
    } else {
        const float* xp = src + (size_t)b * T_LEN * C_DIM + c;
        for (int e = tid; e < 4096; e += 256) {
            int r = (int)(__brev((unsigned)e) >> 20);
            re[FPAD(r)] = xp[(size_t)e * C_DIM];
        }
    }
    __syncthreads();

#pragma unroll
    for (int sp = 0; sp < 6; sp++) {
        const int h = 1 << (2 * sp);
        const int t1s = 11 - 2 * sp;
        const int t2s = 10 - 2 * sp;
        for (int j = tid; j < 1024; j += 256) {
            int p = j & (h - 1);
            int G = j >> (2 * sp);
            int base = G * 4 * h + p;
            int iA = FPAD(base), iB = FPAD(base + h);
            int iC = FPAD(base + 2 * h), iD = FPAD(base + 3 * h);
            float w1r = twr[p << t1s], w1i = twi[p << t1s];
            float w2r = twr[p << t2s], w2i = twi[p << t2s];
            float Ar = re[iA], Ai = im[iA], Br = re[iB], Bi = im[iB];
            float Cr = re[iC], Ci = im[iC], Dr = re[iD], Di = im[iD];
            float tBr = w1r * Br - w1i * Bi, tBi = w1r * Bi + w1i * Br;
            float tDr = w1r * Dr - w1i * Di, tDi = w1r * Di + w1i * Dr;
            float A1r = Ar + tBr, A1i = Ai + tBi;
            float B1r = Ar - tBr, B1i = Ai - tBi;
            float C1r = Cr + tDr, C1i = Ci + tDi;
            float D1r = Cr - tDr, D1i = Ci - tDi;
            float tCr = w2r * C1r - w2i * C1i, tCi = w2r * C1i + w2i * C1r;
            float uDr = w2r * D1r - w2i * D1i, uDi = w2r * D1i + w2i * D1r;
            float vDr = uDi, vDi = -uDr;
            re[iA] = A1r + tCr; im[iA] = A1i + tCi;
            re[iC] = A1r - tCr; im[iC] = A1i - tCi;
            re[iB] = B1r + vDr; im[iB] = B1i + vDi;
            re[iD] = B1r - vDr; im[iD] = B1i - vDi;
        }
        __syncthreads();
    }

    unsigned short* mp = mags + ((size_t)(b * C_DIM + c)) * 2048;
    for (int u = tid; u < 2048; u += 256) {
        int f = FPAD(u + 1);
        mp[u] = f2bf(sqrtf(re[f] * re[f] + im[f] * im[f]));
    }
}

// ------------------------------------------------------------------
// partial[b][cc][u] = sum over 32 channels of mags (bf16 in, fp32 out)
// ------------------------------------------------------------------
__global__ __launch_bounds__(256) void reduce_amps_kernel(const unsigned short* __restrict__ mags,
                                                          float* __restrict__ partial) {
    const int b = blockIdx.z, cc = blockIdx.y;
    const int u = blockIdx.x * 256 + threadIdx.x;
    const unsigned short* mp = mags + ((size_t)b * C_DIM + cc * 32) * 2048 + u;
    float s = 0.0f;
    for (int c = 0; c < 32; c++) s += bf2f(mp[(size_t)c * 2048]);
    partial[((size_t)b * 8 + cc) * 2048 + u] = s;
}

// ------------------------------------------------------------------
// Per-batch top-4 (value desc, ties -> lower index), periods, softmax
// ------------------------------------------------------------------
__global__ __launch_bounds__(256) void topk_kernel(const float* __restrict__ partial,
                                                   int* __restrict__ meta_p,
                                                   float* __restrict__ meta_w) {
    const int b = blockIdx.x;
    const int tid = threadIdx.x;
    __shared__ float v[2048];
    __shared__ float rv[256];
    __shared__ int ri[256];
    __shared__ float topv[K_TOP];
    __shared__ int topi[K_TOP];

    for (int u = tid; u < 2048; u += 256) {
        float s = 0.0f;
        for (int cc = 0; cc < 8; cc++) s += partial[((size_t)b * 8 + cc) * 2048 + u];
        v[u] = s * (1.0f / (float)C_DIM);
    }

    for (int k = 0; k < K_TOP; k++) {
        __syncthreads();
        float bv = -1e30f;
        int bi = 2048;
        for (int u = tid; u < 2048; u += 256) {
            float val = v[u];
            if (val > bv) { bv = val; bi = u; }
        }
        rv[tid] = bv;
        ri[tid] = bi;
        __syncthreads();
        for (int s = 128; s > 0; s >>= 1) {
            if (tid < s) {
                float ov = rv[tid + s];
                int oi = ri[tid + s];
                if (ov > rv[tid] || (ov == rv[tid] && oi < ri[tid])) {
                    rv[tid] = ov;
                    ri[tid] = oi;
                }
            }
            __syncthreads();
        }
        if (tid == 0) {
            topv[k] = rv[0];
            topi[k] = ri[0];
            v[ri[0]] = -1e30f;
        }
    }
    __syncthreads();
    if (tid == 0) {
        float mx = topv[0];
        for (int k = 1; k < K_TOP; k++) mx = fmaxf(mx, topv[k]);
        float e[K_TOP], se = 0.0f;
        for (int k = 0; k < K_TOP; k++) { e[k] = expf(topv[k] - mx); se += e[k]; }
        for (int k = 0; k < K_TOP; k++) {
            int idx = topi[k];
            int d = (idx >= 1) ? idx : 1;
            int p = T_LEN / d;
            if (p < 1) p = 1;
            meta_p[b * K_TOP + k] = p;
            meta_w[b * K_TOP + k] = e[k] / se;
        }
    }
}

// ------------------------------------------------------------------
// Conv as MFMA GEMM (round-11 version, the measured-176us structure):
// 128x256 tile, 512 thr / 8 waves (wave tile 64x64), 3-buffer LDS
// pipeline (stage s+2 while computing s), counted vmcnt(3) barriers,
// zero-conflict swizzle key (row>>1)&3, setprio around MFMA, gelu_fast.
// LDS 72 KB -> 2 blocks/CU (barrier-stall overlap between blocks).
// ------------------------------------------------------------------
__global__ __launch_bounds__(512) void conv_mfma_kernel(const unsigned short* __restrict__ xbf,
                                                        const unsigned short* __restrict__ WcT,
                                                        const float* __restrict__ bc,
                                                        const int* __restrict__ meta_p,
                                                        const unsigned short* __restrict__ zbuf,
                                                        unsigned short* __restrict__ convbufs,
                                                        size_t conv_stride, int koff) {
    const int b = blockIdx.y;
    const int kz = blockIdx.z;
    const int n = meta_p[b * K_TOP + koff + kz];
    const int row0 = blockIdx.x * 128;
    const int tid = threadIdx.x, w = tid >> 6, lane = tid & 63;
    const int wm = w >> 2, wn = w & 3;

    __shared__ __align__(16) unsigned short Al[3][128 * 32];
    __shared__ __align__(16) unsigned short Bl[3][256 * 32];

    const int ra = tid >> 2;
    const int swz = ((tid & 3) ^ ((ra >> 1) & 3)) * 8;
    int ti, tj;
    {
        int t = row0 + ra;
        ti = t / n;
        tj = t - ti * n;
    }
    const unsigned short* xb = xbf + (size_t)b * T_LEN * C_DIM;
    const unsigned short* baseB0 = WcT + (size_t)ra * 2304 + swz;
    const unsigned short* baseB1 = WcT + (size_t)(ra + 128) * 2304 + swz;

    auto computeA = [&](int q) -> const unsigned short* {
        int di = q / 3 - 1, dj = q % 3 - 1;
        int ii = ti + di, jj = tj + dj;
        int tp = ii * n + jj;
        bool ok = (jj >= 0) && (jj < n) && (ii >= 0) && (tp < T_LEN);
        return ok ? (xb + (size_t)tp * C_DIM + swz) : (zbuf + swz);
    };

    f32x4 acc[4][4];
#pragma unroll
    for (int m = 0; m < 4; m++)
#pragma unroll
        for (int nn = 0; nn < 4; nn++) acc[m][nn] = (f32x4){0.f, 0.f, 0.f, 0.f};

    const unsigned short* baseA = computeA(0);
    lds_load16(baseA, &Al[0][tid * 8]);
    lds_load16(baseB0, &Bl[0][tid * 8]);
    lds_load16(baseB1, &Bl[0][4096 + tid * 8]);
    lds_load16(baseA + 32, &Al[1][tid * 8]);
    lds_load16(baseB0 + 32, &Bl[1][tid * 8]);
    lds_load16(baseB1 + 32, &Bl[1][4096 + tid * 8]);

    int cur = 0, stb = 2;
    for (int s = 0; s < 72; s++) {
        if (s < 71) BAR_VM3();
        else        BAR_VM0();

        const int t = s + 2;
        if (t < 72) {
            if ((t & 7) == 0) baseA = computeA(t >> 3);
            lds_load16(baseA + (t & 7) * 32, &Al[stb][tid * 8]);
            lds_load16(baseB0 + (size_t)t * 32, &Bl[stb][tid * 8]);
            lds_load16(baseB1 + (size_t)t * 32, &Bl[stb][4096 + tid * 8]);
        }

        bf16x8 af[4], bfr[4];
#pragma unroll
        for (int m = 0; m < 4; m++) {
            int row = wm * 64 + m * 16 + (lane & 15);
            af[m] = *(const bf16x8*)((const char*)&Al[cur][0] + row * 64 +
                                     (((lane >> 4) * 16) ^ (((row >> 1) & 3) << 4)));
        }
#pragma unroll
        for (int nn = 0; nn < 4; nn++) {
            int rowb = wn * 64 + nn * 16 + (lane & 15);
            bfr[nn] = *(const bf16x8*)((const char*)&Bl[cur][0] + rowb * 64 +
                                       (((lane >> 4) * 16) ^ (((rowb >> 1) & 3) << 4)));
        }
        __builtin_amdgcn_s_setprio(1);
#pragma unroll
        for (int m = 0; m < 4; m++)
#pragma unroll
            for (int nn = 0; nn < 4; nn++)
                acc[m][nn] = __builtin_amdgcn_mfma_f32_16x16x32_bf16(af[m], bfr[nn], acc[m][nn], 0, 0, 0);
        __builtin_amdgcn_s_setprio(0);

        cur = (cur == 2) ? 0 : cur + 1;
        stb = (stb == 2) ? 0 : stb + 1;
    }

    unsigned short* ob = convbufs + (size_t)kz * conv_stride + (size_t)b * T_LEN * C_DIM;
#pragma unroll
    for (int nn = 0; nn < 4; nn++) {
        int col = wn * 64 + nn * 16 + (lane & 15);
        float bs = bc[col];
#pragma unroll
        for (int m = 0; m < 4; m++) {
            int rbase = row0 + wm * 64 + m * 16 + (lane >> 4) * 4;
#pragma unroll
            for (int r = 0; r < 4; r++) {
                float v = acc[m][nn][r] + bs;
                ob[(size_t)(rbase + r) * C_DIM + col] = f2bf(gelu_fast(v));
            }
        }
    }
}

// ------------------------------------------------------------------
// Fused FF v5 (round-11, unchanged):
// out = osrc + (sum_k wk*gelu(A_k@W1+b1)) @ W2 + b2scale*b2
// ------------------------------------------------------------------
template <int KCNT>
__global__ __launch_bounds__(256, 2) void fused_ff_kernel(
    const unsigned short* __restrict__ convbufs, size_t conv_stride,
    const unsigned short* __restrict__ W1frag,
    const unsigned short* __restrict__ W2frag,
    const float* __restrict__ b1,
    const float* __restrict__ b2,
    const float* __restrict__ meta_w,
    float* __restrict__ out,
    const float* __restrict__ osrc,   // x (init) or out (accumulate)
    float b2scale, int koff) {
    const int tid = threadIdx.x;
    const int wn = tid >> 6, lane = tid & 63;
    const int row0 = blockIdx.x * 32;
    const int b = row0 >> 12;

    __shared__ __align__(16) unsigned short Asw[KCNT * 32 * 256];   // KCNT*16 KB
    __shared__ __align__(16) unsigned short Hsw[2][32 * 128];       // 2 x 8 KB

    float wkv[KCNT];
#pragma unroll
    for (int kc = 0; kc < KCNT; kc++) wkv[kc] = meta_w[b * K_TOP + koff + kc];

    // ---- stage all KCNT A-strips once (linear LDS dest, inv-swizzled src) ----
    {
        const unsigned short* base = convbufs + (size_t)row0 * C_DIM;
#pragma unroll
        for (int u = 0; u < KCNT * 4; u++) {
            int ch = u * 256 + tid;      // 16B chunk id
            int rfull = ch >> 5;         // row in Asw (= kc*32 + trow)
            int kc = rfull >> 5;
            int trow = rfull & 31;
            int cole = ((ch & 31) * 8) ^ ((rfull & 7) << 3);
            lds_load16(base + (size_t)kc * conv_stride + (size_t)trow * 256 + cole,
                       (unsigned short*)Asw + (size_t)ch * 8);
        }
    }

    f32x4 acc2[2][4];
#pragma unroll
    for (int t2 = 0; t2 < 2; t2++)
#pragma unroll
        for (int nn = 0; nn < 4; nn++) acc2[t2][nn] = (f32x4){0.f, 0.f, 0.f, 0.f};

    BAR_VM0();  // Asw landed

    for (int cc = 0; cc < 8; cc++) {
        const int par = cc & 1;

        // ---- GEMM1 (swapped) over all k: acc1[kc][n2][t2] = H^T frags ----
        f32x4 acc1[KCNT][2][2];
#pragma unroll
        for (int kc = 0; kc < KCNT; kc++)
#pragma unroll
            for (int n2 = 0; n2 < 2; n2++)
#pragma unroll
                for (int t2 = 0; t2 < 2; t2++) acc1[kc][n2][t2] = (f32x4){0.f, 0.f, 0.f, 0.f};

        __builtin_amdgcn_s_setprio(1);
#pragma unroll
        for (int ks = 0; ks < 8; ks++) {
            bf16x8 w1f[2];
#pragma unroll
            for (int n2 = 0; n2 < 2; n2++) {
                int tile_n = cc * 8 + wn * 2 + n2;
                w1f[n2] = *(const bf16x8*)(W1frag + ((size_t)(tile_n * 8 + ks) * 64 + lane) * 8);
            }
            bf16x8 af[KCNT][2];
#pragma unroll
            for (int kc = 0; kc < KCNT; kc++)
#pragma unroll
                for (int t2 = 0; t2 < 2; t2++) {
                    int row = kc * 32 + t2 * 16 + (lane & 15);
                    af[kc][t2] = *(const bf16x8*)((const char*)Asw + row * 512 +
                                                  ((ks * 64 + (lane >> 4) * 16) ^ ((row & 7) << 4)));
                }
#pragma unroll
            for (int kc = 0; kc < KCNT; kc++)
#pragma unroll
                for (int n2 = 0; n2 < 2; n2++)
#pragma unroll
                    for (int t2 = 0; t2 < 2; t2++)
                        acc1[kc][n2][t2] = __builtin_amdgcn_mfma_f32_16x16x32_bf16(
                            w1f[n2], af[kc][t2], acc1[kc][n2][t2], 0, 0, 0);
        }
        __builtin_amdgcn_s_setprio(0);

        // ---- combine: Hsw[par][t][h] = sum_k wk*gelu(acc1 + b1) (bf16) ----
#pragma unroll
        for (int n2 = 0; n2 < 2; n2++) {
            const int hloc = wn * 32 + n2 * 16 + (lane >> 4) * 4;  // 4 consecutive h
            f32x4 bb = *(const f32x4*)(b1 + cc * 128 + hloc);
#pragma unroll
            for (int t2 = 0; t2 < 2; t2++) {
                float hc[4];
#pragma unroll
                for (int r = 0; r < 4; r++) {
                    float s = 0.0f;
#pragma unroll
                    for (int kc = 0; kc < KCNT; kc++)
                        s += wkv[kc] * gelu_fast(acc1[kc][n2][t2][r] + bb[r]);
                    hc[r] = s;
                }
                uint32_t lo, hi;
                asm("v_cvt_pk_bf16_f32 %0, %1, %2" : "=v"(lo) : "v"(hc[0]), "v"(hc[1]));
                asm("v_cvt_pk_bf16_f32 %0, %1, %2" : "=v"(hi) : "v"(hc[2]), "v"(hc[3]));
                uint2 pk;
                pk.x = lo;
                pk.y = hi;
                int t = t2 * 16 + (lane & 15);
                *(uint2*)((char*)&Hsw[par][0] + t * 256 +
                          ((hloc * 2) ^ ((t & 7) << 4))) = pk;
            }
        }
        BAR_LGKM();  // Hsw[par] visible; global prefetches stay in flight

        // ---- GEMM2 once per chunk: acc2 += Hcomb @ W2chunk ----
        __builtin_amdgcn_s_setprio(1);
#pragma unroll
        for (int ks2 = 0; ks2 < 4; ks2++) {
            bf16x8 af2[2], w2f[4];
#pragma unroll
            for (int t2 = 0; t2 < 2; t2++) {
                int row = t2 * 16 + (lane & 15);
                af2[t2] = *(const bf16x8*)((const char*)&Hsw[par][0] + row * 256 +
                                           ((ks2 * 64 + (lane >> 4) * 16) ^ ((row & 7) << 4)));
            }
#pragma unroll
            for (int nn = 0; nn < 4; nn++) {
                int tile_n = wn * 4 + nn;
                int tile_k = cc * 4 + ks2;
                w2f[nn] = *(const bf16x8*)(W2frag + ((size_t)(tile_n * 32 + tile_k) * 64 + lane) * 8);
            }
#pragma unroll
            for (int t2 = 0; t2 < 2; t2++)
#pragma unroll
                for (int nn = 0; nn < 4; nn++)
                    acc2[t2][nn] = __builtin_amdgcn_mfma_f32_16x16x32_bf16(af2[t2], w2f[nn],
                                                                           acc2[t2][nn], 0, 0, 0);
        }
        __builtin_amdgcn_s_setprio(0);
        // no barrier: next chunk writes Hsw[par^1], whose readers (GEMM2 at
        // cc-1) are ordered before the BAR_LGKM above.
    }

    // ---- epilogue: out = osrc + acc2 + b2scale*b2 ----
#pragma unroll
    for (int nn = 0; nn < 4; nn++) {
        int col = wn * 64 + nn * 16 + (lane & 15);
        float bb = b2scale * b2[col];
#pragma unroll
        for (int t2 = 0; t2 < 2; t2++) {
            int rbase = row0 + t2 * 16 + (lane >> 4) * 4;
#pragma unroll
            for (int r = 0; r < 4; r++) {
                size_t idx = (size_t)(rbase + r) * C_DIM + col;
                out[idx] = osrc[idx] + acc2[t2][nn][r] + bb;
            }
        }
    }
}

// ------------------------------------------------------------------
extern "C" void kernel_launch(void* const* d_in, const int* in_sizes, int n_in,
                              void* d_out, int out_size, void* d_ws, size_t ws_size,
                              hipStream_t stream) {
    const float* x  = (const float*)d_in[0];
    const float* Wc = (const float*)d_in[1];
    const float* bc = (const float*)d_in[2];
    const float* W1 = (const float*)d_in[3];
    const float* b1 = (const float*)d_in[4];
    const float* W2 = (const float*)d_in[5];
    const float* b2 = (const float*)d_in[6];
    float* out = (float*)d_out;

    const size_t CONV_ELEMS = (size_t)B_DIM * T_LEN * C_DIM;     // 8M
    const size_t CONV_BYTES = CONV_ELEMS * 2;                    // 16.78 MB
    const size_t MAGS_BYTES = (size_t)B_DIM * C_DIM * 2048 * 2;  // 8.39 MB (bf16)
    const size_t XT_BYTES = (size_t)B_DIM * T_LEN * C_DIM * 4;   // 33.55 MB

    // ---- fixed carve ----
    uint8_t* ws = (uint8_t*)d_ws;
    size_t off = 0;
    auto alloc = [&](size_t bytes) {
        size_t o = off;
        off = (off + bytes + 255) & ~(size_t)255;
        return o;
    };
    float* partial = (float*)(ws + alloc((size_t)B_DIM * 8 * 2048 * 4));
    int* meta_p = (int*)(ws + alloc(B_DIM * K_TOP * 4));
    float* meta_w = (float*)(ws + alloc(B_DIM * K_TOP * 4));
    unsigned short* xbf = (unsigned short*)(ws + alloc((size_t)B_DIM * T_LEN * C_DIM * 2));
    unsigned short* WcT = (unsigned short*)(ws + alloc((size_t)256 * 2304 * 2));
    unsigned short* W1frag = (unsigned short*)(ws + alloc((size_t)256 * 1024 * 2));
    unsigned short* W2frag = (unsigned short*)(ws + alloc((size_t)1024 * 256 * 2));
    unsigned short* zbuf = (unsigned short*)(ws + alloc(512));

    // ---- tiered regionA ----
    size_t remaining = (ws_size > off) ? (ws_size - off) : 0;
    uint8_t* regionA = ws + off;
    int tier;  // 2=FULL(4 convbufs), 1=MID(1 convbuf + xT), 0=MIN
    if (remaining >= 4 * CONV_BYTES) tier = 2;
    else if (remaining >= MAGS_BYTES + XT_BYTES) tier = 1;
    else tier = 0;

    unsigned short* mags = (unsigned short*)regionA;  // FFT phase (dead before conv)
    float* xT = (float*)(regionA + ((tier == 2) ? CONV_BYTES : MAGS_BYTES));
    unsigned short* convbufs = (unsigned short*)regionA;
    const int use_xT = (tier >= 1);

    // 1. x -> {xT, xbf, zbuf} in one read (fused); fallback: xbf only
    if (use_xT) {
        transpose_cvtx_kernel<<<dim3(T_LEN / 32, C_DIM / 32, B_DIM), 256, 0, stream>>>(
            x, xT, xbf, zbuf);
    } else {
        cvt_x_kernel<<<dim3((B_DIM * T_LEN * C_DIM / 4) / 256), 256, 0, stream>>>(
            (const float4*)x, (ushort4*)xbf, zbuf);
    }

    // 2. weight prep
    transpose_cvt_kernel<<<dim3(256 / 32, 2304 / 32), 256, 0, stream>>>(Wc, WcT, 2304, 256);
    repack_frag_kernel<<<dim3(128), 256, 0, stream>>>(W1, W1frag, 256, 1024);
    repack_frag_kernel<<<dim3(128), 256, 0, stream>>>(W2, W2frag, 1024, 256);

    // 3. FFT magnitudes (bf16), reduce, top-4
    if (use_xT) {
        fft_mag_kernel<<<dim3(B_DIM * C_DIM), 256, 0, stream>>>(xT, mags, 1);
    } else {
        fft_mag_kernel<<<dim3(B_DIM * C_DIM), 256, 0, stream>>>(x, mags, 0);
    }
    reduce_amps_kernel<<<dim3(2048 / 256, 8, B_DIM), 256, 0, stream>>>(mags, partial);
    topk_kernel<<<dim3(B_DIM), 256, 0, stream>>>(partial, meta_p, meta_w);

    // 4. conv (all k) then fused FF (combined over k)
    if (tier == 2) {
        conv_mfma_kernel<<<dim3(32, B_DIM, K_TOP), 512, 0, stream>>>(
            xbf, WcT, bc, meta_p, zbuf, convbufs, CONV_ELEMS, 0);
        fused_ff_kernel<4><<<dim3(B_DIM * T_LEN / 32), 256, 0, stream>>>(
            convbufs, CONV_ELEMS, W1frag, W2frag, b1, b2, meta_w, out, x, 1.0f, 0);
    } else {
        for (int k = 0; k < K_TOP; k++) {
            conv_mfma_kernel<<<dim3(32, B_DIM, 1), 512, 0, stream>>>(
                xbf, WcT, bc, meta_p, zbuf, convbufs, 0, k);
            fused_ff_kernel<1><<<dim3(B_DIM * T_LEN / 32), 256, 0, stream>>>(
                convbufs, 0, W1frag, W2frag, b1, b2, meta_w, out,
                (k == 0) ? x : out, (k == K_TOP - 1) ? 1.0f : 0.0f, k);
        }
    }
}

// Round 14
// 384.867 us; speedup vs baseline: 1.0531x; 1.0010x over previous
//
#include <hip/hip_runtime.h>
#include <cstdint>
#include <cstddef>

#define T_LEN 4096
#define C_DIM 256
#define B_DIM 8
#define K_TOP 4

typedef __attribute__((ext_vector_type(8))) short bf16x8;
typedef __attribute__((ext_vector_type(4))) float f32x4;

// tanh-form GELU: x * sigmoid(1.59577x + 0.0713548x^3); |delta| vs exact
// erf-GELU ~2.5e-4, below the bf16 quant noise already in the buffers.
__device__ __forceinline__ float gelu_fast(float x) {
    float x2 = x * x;
    float a = x * fmaf(0.071354816f, x2, 1.595769122f);
    float e = __expf(-a);
    return __fdividef(x, 1.0f + e);
}

__device__ __forceinline__ unsigned short f2bf(float f) {
    uint32_t u = __float_as_uint(f);
    uint32_t r = (u + 0x7fffu + ((u >> 16) & 1u)) >> 16;
    return (unsigned short)r;
}

__device__ __forceinline__ float bf2f(unsigned short v) {
    uint32_t u = ((uint32_t)v) << 16;
    return __uint_as_float(u);
}

typedef __attribute__((address_space(3))) uint32_t lds_u32_t;
typedef __attribute__((address_space(1))) const uint32_t gbl_u32_t;

__device__ __forceinline__ void lds_load16(const void* g, void* l) {
    __builtin_amdgcn_global_load_lds((gbl_u32_t*)g, (lds_u32_t*)l, 16, 0, 0);
}

// raw barriers with explicit (counted) waits
#define BAR_VM0()                                                      \
    do {                                                               \
        asm volatile("s_waitcnt vmcnt(0) lgkmcnt(0)" ::: "memory");    \
        __builtin_amdgcn_s_barrier();                                  \
        __builtin_amdgcn_sched_barrier(0);                             \
    } while (0)
#define BAR_VM3()                                                      \
    do {                                                               \
        asm volatile("s_waitcnt vmcnt(3) lgkmcnt(0)" ::: "memory");    \
        __builtin_amdgcn_s_barrier();                                  \
        __builtin_amdgcn_sched_barrier(0);                             \
    } while (0)
#define BAR_LGKM()                                                     \
    do {                                                               \
        asm volatile("s_waitcnt lgkmcnt(0)" ::: "memory");             \
        __builtin_amdgcn_s_barrier();                                  \
        __builtin_amdgcn_sched_barrier(0);                             \
    } while (0)

// padded LDS index for FFT: +1 float per 32
#define FPAD(i) ((i) + ((i) >> 5))

// ------------------------------------------------------------------
// Fallback (no-xT tier): xbf = bf16(x), plus zero page
// ------------------------------------------------------------------
__global__ __launch_bounds__(256) void cvt_x_kernel(const float4* __restrict__ x,
                                                    ushort4* __restrict__ xbf,
                                                    unsigned short* __restrict__ zbuf) {
    size_t i = (size_t)blockIdx.x * 256 + threadIdx.x;
    float4 v = x[i];
    ushort4 o;
    o.x = f2bf(v.x); o.y = f2bf(v.y); o.z = f2bf(v.z); o.w = f2bf(v.w);
    xbf[i] = o;
    if (blockIdx.x == 0 && threadIdx.x < 256) zbuf[threadIdx.x] = 0;
}

// ------------------------------------------------------------------
// Fused: one read of x produces xT[b][c][t] (fp32, for FFT) AND
// xbf[b][t][c] (bf16, for conv), plus the zero page.
// ------------------------------------------------------------------
__global__ __launch_bounds__(256) void transpose_cvtx_kernel(const float* __restrict__ x,
                                                             float* __restrict__ xT,
                                                             unsigned short* __restrict__ xbf,
                                                             unsigned short* __restrict__ zbuf) {
    __shared__ float tile[32][33];
    const int b = blockIdx.z;
    const int t0 = blockIdx.x * 32, c0 = blockIdx.y * 32;
    const int lx = threadIdx.x & 31, ly = threadIdx.x >> 5;
    const float* xp = x + (size_t)b * T_LEN * C_DIM;
    unsigned short* xbp = xbf + (size_t)b * T_LEN * C_DIM;
    float* op = xT + (size_t)b * C_DIM * T_LEN;
    for (int rr = ly; rr < 32; rr += 8) {
        float v = xp[(size_t)(t0 + rr) * C_DIM + c0 + lx];
        tile[rr][lx] = v;
        xbp[(size_t)(t0 + rr) * C_DIM + c0 + lx] = f2bf(v);
    }
    __syncthreads();
    for (int rr = ly; rr < 32; rr += 8)
        op[(size_t)(c0 + rr) * T_LEN + t0 + lx] = tile[lx][rr];
    if (blockIdx.x == 0 && blockIdx.y == 0 && blockIdx.z == 0)
        zbuf[threadIdx.x] = 0;
}

// ------------------------------------------------------------------
// fp32 [R][C] -> bf16 transposed [C][R]   (conv weights)
// ------------------------------------------------------------------
__global__ __launch_bounds__(256) void transpose_cvt_kernel(const float* __restrict__ src,
                                                            unsigned short* __restrict__ dst,
                                                            int R, int C) {
    __shared__ float t[32][33];
    const int c0 = blockIdx.x * 32, r0 = blockIdx.y * 32;
    const int lx = threadIdx.x & 31, ly = threadIdx.x >> 5;
    for (int rr = ly; rr < 32; rr += 8) {
        int r = r0 + rr, c = c0 + lx;
        t[rr][lx] = (r < R && c < C) ? src[(size_t)r * C + c] : 0.0f;
    }
    __syncthreads();
    for (int rr = ly; rr < 32; rr += 8) {
        int c = c0 + rr, r = r0 + lx;
        if (r < R && c < C) dst[(size_t)c * R + r] = f2bf(t[lx][rr]);
    }
}

// ------------------------------------------------------------------
// fp32 src[K][N] -> bf16 MFMA fragment tiles (A- and B-compatible).
// ------------------------------------------------------------------
__global__ __launch_bounds__(256) void repack_frag_kernel(const float* __restrict__ src,
                                                          unsigned short* __restrict__ dst,
                                                          int K, int N) {
    int idx = blockIdx.x * 256 + threadIdx.x;  // (tile, lane)
    int total = (N >> 4) * (K >> 5) * 64;
    if (idx >= total) return;
    int lane = idx & 63, tile = idx >> 6;
    int ktiles = K >> 5;
    int tile_n = tile / ktiles, tile_k = tile % ktiles;
    int col = tile_n * 16 + (lane & 15);
    int k0 = tile_k * 32 + (lane >> 4) * 8;
    __align__(16) unsigned short v[8];
#pragma unroll
    for (int j = 0; j < 8; j++) v[j] = f2bf(src[(size_t)(k0 + j) * N + col]);
    *(uint4*)(dst + (size_t)idx * 8) = *(const uint4*)v;
}

// ------------------------------------------------------------------
// Per-(b,c) 4096-pt FFT, fused radix-2 stage-pairs, pad-32 LDS.
// Writes |X_f| as bf16 (consumed only by a mean; 1.2e-4 relative
// noise after channel-mean vs ~1% top-k gaps -> 50-100x margin).
// ------------------------------------------------------------------
__global__ __launch_bounds__(256) void fft_mag_kernel(const float* __restrict__ src,
                                                      unsigned short* __restrict__ mags,
                                                      int transposed) {
    const int bx = blockIdx.x;
    const int b = bx >> 8;
    const int c = bx & 255;
    const int tid = threadIdx.x;

    __shared__ __align__(16) float re[4224];
    __shared__ __align__(16) float im[4224];
    __shared__ __align__(16) float twr[2048];
    __shared__ __align__(16) float twi[2048];

    for (int u = tid; u < 2048; u += 256) {
        float ang = -6.283185307179586f * (float)u / 4096.0f;
        float s, co;
        sincosf(ang, &s, &co);
        twr[u] = co;
        twi[u] = s;
    }
    for (int i = tid; i < 4224; i += 256) im[i] = 0.0f;

    if (transposed) {
        const float4* row = (const float4*)(src + ((size_t)(b * C_DIM + c)) * T_LEN);
        for (int e4 = tid; e4 < 1024; e4 += 256) {
            float4 v = row[e4];
            int e = e4 * 4;
            re[FPAD((int)(__brev((unsigned)(e + 0)) >> 20))] = v.x;
            re[FPAD((int)(__brev((unsigned)(e + 1)) >> 20))] = v.y;
            re[FPAD((int)(__brev((unsigned)(e + 2)) >> 20))] = v.z;
            re[FPAD((int)(__brev((unsigned)(e + 3)) >> 20))] = v.w;
        }
    } else {
        const float* xp = src + (size_t)b * T_LEN * C_DIM + c;
        for (int e = tid; e < 4096; e += 256) {
            int r = (int)(__brev((unsigned)e) >> 20);
            re[FPAD(r)] = xp[(size_t)e * C_DIM];
        }
    }
    __syncthreads();

#pragma unroll
    for (int sp = 0; sp < 6; sp++) {
        const int h = 1 << (2 * sp);
        const int t1s = 11 - 2 * sp;
        const int t2s = 10 - 2 * sp;
        for (int j = tid; j < 1024; j += 256) {
            int p = j & (h - 1);
            int G = j >> (2 * sp);
            int base = G * 4 * h + p;
            int iA = FPAD(base), iB = FPAD(base + h);
            int iC = FPAD(base + 2 * h), iD = FPAD(base + 3 * h);
            float w1r = twr[p << t1s], w1i = twi[p << t1s];
            float w2r = twr[p << t2s], w2i = twi[p << t2s];
            float Ar = re[iA], Ai = im[iA], Br = re[iB], Bi = im[iB];
            float Cr = re[iC], Ci = im[iC], Dr = re[iD], Di = im[iD];
            float tBr = w1r * Br - w1i * Bi, tBi = w1r * Bi + w1i * Br;
            float tDr = w1r * Dr - w1i * Di, tDi = w1r * Di + w1i * Dr;
            float A1r = Ar + tBr, A1i = Ai + tBi;
            float B1r = Ar - tBr, B1i = Ai - tBi;
            float C1r = Cr + tDr, C1i = Ci + tDi;
            float D1r = Cr - tDr, D1i = Ci - tDi;
            float tCr = w2r * C1r - w2i * C1i, tCi = w2r * C1i + w2i * C1r;
            float uDr = w2r * D1r - w2i * D1i, uDi = w2r * D1i + w2i * D1r;
            float vDr = uDi, vDi = -uDr;
            re[iA] = A1r + tCr; im[iA] = A1i + tCi;
            re[iC] = A1r - tCr; im[iC] = A1i - tCi;
            re[iB] = B1r + vDr; im[iB] = B1i + vDi;
            re[iD] = B1r - vDr; im[iD] = B1i - vDi;
        }
        __syncthreads();
    }

    unsigned short* mp = mags + ((size_t)(b * C_DIM + c)) * 2048;
    for (int u = tid; u < 2048; u += 256) {
        int f = FPAD(u + 1);
        mp[u] = f2bf(sqrtf(re[f] * re[f] + im[f] * im[f]));
    }
}

// ------------------------------------------------------------------
// partial[b][cc][u] = sum over 32 channels of mags (bf16 in, fp32 out)
// ------------------------------------------------------------------
__global__ __launch_bounds__(256) void reduce_amps_kernel(const unsigned short* __restrict__ mags,
                                                          float* __restrict__ partial) {
    const int b = blockIdx.z, cc = blockIdx.y;
    const int u = blockIdx.x * 256 + threadIdx.x;
    const unsigned short* mp = mags + ((size_t)b * C_DIM + cc * 32) * 2048 + u;
    float s = 0.0f;
    for (int c = 0; c < 32; c++) s += bf2f(mp[(size_t)c * 2048]);
    partial[((size_t)b * 8 + cc) * 2048 + u] = s;
}

// ------------------------------------------------------------------
// Per-batch top-4 (value desc, ties -> lower index), periods, softmax
// ------------------------------------------------------------------
__global__ __launch_bounds__(256) void topk_kernel(const float* __restrict__ partial,
                                                   int* __restrict__ meta_p,
                                                   float* __restrict__ meta_w) {
    const int b = blockIdx.x;
    const int tid = threadIdx.x;
    __shared__ float v[2048];
    __shared__ float rv[256];
    __shared__ int ri[256];
    __shared__ float topv[K_TOP];
    __shared__ int topi[K_TOP];

    for (int u = tid; u < 2048; u += 256) {
        float s = 0.0f;
        for (int cc = 0; cc < 8; cc++) s += partial[((size_t)b * 8 + cc) * 2048 + u];
        v[u] = s * (1.0f / (float)C_DIM);
    }

    for (int k = 0; k < K_TOP; k++) {
        __syncthreads();
        float bv = -1e30f;
        int bi = 2048;
        for (int u = tid; u < 2048; u += 256) {
            float val = v[u];
            if (val > bv) { bv = val; bi = u; }
        }
        rv[tid] = bv;
        ri[tid] = bi;
        __syncthreads();
        for (int s = 128; s > 0; s >>= 1) {
            if (tid < s) {
                float ov = rv[tid + s];
                int oi = ri[tid + s];
                if (ov > rv[tid] || (ov == rv[tid] && oi < ri[tid])) {
                    rv[tid] = ov;
                    ri[tid] = oi;
                }
            }
            __syncthreads();
        }
        if (tid == 0) {
            topv[k] = rv[0];
            topi[k] = ri[0];
            v[ri[0]] = -1e30f;
        }
    }
    __syncthreads();
    if (tid == 0) {
        float mx = topv[0];
        for (int k = 1; k < K_TOP; k++) mx = fmaxf(mx, topv[k]);
        float e[K_TOP], se = 0.0f;
        for (int k = 0; k < K_TOP; k++) { e[k] = expf(topv[k] - mx); se += e[k]; }
        for (int k = 0; k < K_TOP; k++) {
            int idx = topi[k];
            int d = (idx >= 1) ? idx : 1;
            int p = T_LEN / d;
            if (p < 1) p = 1;
            meta_p[b * K_TOP + k] = p;
            meta_w[b * K_TOP + k] = e[k] / se;
        }
    }
}

// ------------------------------------------------------------------
// Conv as MFMA GEMM (round-11 version, the measured-176us structure):
// 128x256 tile, 512 thr / 8 waves (wave tile 64x64), 3-buffer LDS
// pipeline (stage s+2 while computing s), counted vmcnt(3) barriers,
// zero-conflict swizzle key (row>>1)&3, setprio around MFMA, gelu_fast.
// LDS 72 KB -> 2 blocks/CU (barrier-stall overlap between blocks).
// ------------------------------------------------------------------
__global__ __launch_bounds__(512) void conv_mfma_kernel(const unsigned short* __restrict__ xbf,
                                                        const unsigned short* __restrict__ WcT,
                                                        const float* __restrict__ bc,
                                                        const int* __restrict__ meta_p,
                                                        const unsigned short* __restrict__ zbuf,
                                                        unsigned short* __restrict__ convbufs,
                                                        size_t conv_stride, int koff) {
    const int b = blockIdx.y;
    const int kz = blockIdx.z;
    const int n = meta_p[b * K_TOP + koff + kz];
    const int row0 = blockIdx.x * 128;
    const int tid = threadIdx.x, w = tid >> 6, lane = tid & 63;
    const int wm = w >> 2, wn = w & 3;

    __shared__ __align__(16) unsigned short Al[3][128 * 32];
    __shared__ __align__(16) unsigned short Bl[3][256 * 32];

    const int ra = tid >> 2;
    const int swz = ((tid & 3) ^ ((ra >> 1) & 3)) * 8;
    int ti, tj;
    {
        int t = row0 + ra;
        ti = t / n;
        tj = t - ti * n;
    }
    const unsigned short* xb = xbf + (size_t)b * T_LEN * C_DIM;
    const unsigned short* baseB0 = WcT + (size_t)ra * 2304 + swz;
    const unsigned short* baseB1 = WcT + (size_t)(ra + 128) * 2304 + swz;

    auto computeA = [&](int q) -> const unsigned short* {
        int di = q / 3 - 1, dj = q % 3 - 1;
        int ii = ti + di, jj = tj + dj;
        int tp = ii * n + jj;
        bool ok = (jj >= 0) && (jj < n) && (ii >= 0) && (tp < T_LEN);
        return ok ? (xb + (size_t)tp * C_DIM + swz) : (zbuf + swz);
    };

    f32x4 acc[4][4];
#pragma unroll
    for (int m = 0; m < 4; m++)
#pragma unroll
        for (int nn = 0; nn < 4; nn++) acc[m][nn] = (f32x4){0.f, 0.f, 0.f, 0.f};

    const unsigned short* baseA = computeA(0);
    lds_load16(baseA, &Al[0][tid * 8]);
    lds_load16(baseB0, &Bl[0][tid * 8]);
    lds_load16(baseB1, &Bl[0][4096 + tid * 8]);
    lds_load16(baseA + 32, &Al[1][tid * 8]);
    lds_load16(baseB0 + 32, &Bl[1][tid * 8]);
    lds_load16(baseB1 + 32, &Bl[1][4096 + tid * 8]);

    int cur = 0, stb = 2;
    for (int s = 0; s < 72; s++) {
        if (s < 71) BAR_VM3();
        else        BAR_VM0();

        const int t = s + 2;
        if (t < 72) {
            if ((t & 7) == 0) baseA = computeA(t >> 3);
            lds_load16(baseA + (t & 7) * 32, &Al[stb][tid * 8]);
            lds_load16(baseB0 + (size_t)t * 32, &Bl[stb][tid * 8]);
            lds_load16(baseB1 + (size_t)t * 32, &Bl[stb][4096 + tid * 8]);
        }

        bf16x8 af[4], bfr[4];
#pragma unroll
        for (int m = 0; m < 4; m++) {
            int row = wm * 64 + m * 16 + (lane & 15);
            af[m] = *(const bf16x8*)((const char*)&Al[cur][0] + row * 64 +
                                     (((lane >> 4) * 16) ^ (((row >> 1) & 3) << 4)));
        }
#pragma unroll
        for (int nn = 0; nn < 4; nn++) {
            int rowb = wn * 64 + nn * 16 + (lane & 15);
            bfr[nn] = *(const bf16x8*)((const char*)&Bl[cur][0] + rowb * 64 +
                                       (((lane >> 4) * 16) ^ (((rowb >> 1) & 3) << 4)));
        }
        __builtin_amdgcn_s_setprio(1);
#pragma unroll
        for (int m = 0; m < 4; m++)
#pragma unroll
            for (int nn = 0; nn < 4; nn++)
                acc[m][nn] = __builtin_amdgcn_mfma_f32_16x16x32_bf16(af[m], bfr[nn], acc[m][nn], 0, 0, 0);
        __builtin_amdgcn_s_setprio(0);

        cur = (cur == 2) ? 0 : cur + 1;
        stb = (stb == 2) ? 0 : stb + 1;
    }

    unsigned short* ob = convbufs + (size_t)kz * conv_stride + (size_t)b * T_LEN * C_DIM;
#pragma unroll
    for (int nn = 0; nn < 4; nn++) {
        int col = wn * 64 + nn * 16 + (lane & 15);
        float bs = bc[col];
#pragma unroll
        for (int m = 0; m < 4; m++) {
            int rbase = row0 + wm * 64 + m * 16 + (lane >> 4) * 4;
#pragma unroll
            for (int r = 0; r < 4; r++) {
                float v = acc[m][nn][r] + bs;
                ob[(size_t)(rbase + r) * C_DIM + col] = f2bf(gelu_fast(v));
            }
        }
    }
}

// ------------------------------------------------------------------
// Fused FF v5 (round-11, unchanged):
// out = osrc + (sum_k wk*gelu(A_k@W1+b1)) @ W2 + b2scale*b2
// ------------------------------------------------------------------
template <int KCNT>
__global__ __launch_bounds__(256, 2) void fused_ff_kernel(
    const unsigned short* __restrict__ convbufs, size_t conv_stride,
    const unsigned short* __restrict__ W1frag,
    const unsigned short* __restrict__ W2frag,
    const float* __restrict__ b1,
    const float* __restrict__ b2,
    const float* __restrict__ meta_w,
    float* __restrict__ out,
    const float* __restrict__ osrc,   // x (init) or out (accumulate)
    float b2scale, int koff) {
    const int tid = threadIdx.x;
    const int wn = tid >> 6, lane = tid & 63;
    const int row0 = blockIdx.x * 32;
    const int b = row0 >> 12;

    __shared__ __align__(16) unsigned short Asw[KCNT * 32 * 256];   // KCNT*16 KB
    __shared__ __align__(16) unsigned short Hsw[2][32 * 128];       // 2 x 8 KB

    float wkv[KCNT];
#pragma unroll
    for (int kc = 0; kc < KCNT; kc++) wkv[kc] = meta_w[b * K_TOP + koff + kc];

    // ---- stage all KCNT A-strips once (linear LDS dest, inv-swizzled src) ----
    {
        const unsigned short* base = convbufs + (size_t)row0 * C_DIM;
#pragma unroll
        for (int u = 0; u < KCNT * 4; u++) {
            int ch = u * 256 + tid;      // 16B chunk id
            int rfull = ch >> 5;         // row in Asw (= kc*32 + trow)
            int kc = rfull >> 5;
            int trow = rfull & 31;
            int cole = ((ch & 31) * 8) ^ ((rfull & 7) << 3);
            lds_load16(base + (size_t)kc * conv_stride + (size_t)trow * 256 + cole,
                       (unsigned short*)Asw + (size_t)ch * 8);
        }
    }

    f32x4 acc2[2][4];
#pragma unroll
    for (int t2 = 0; t2 < 2; t2++)
#pragma unroll
        for (int nn = 0; nn < 4; nn++) acc2[t2][nn] = (f32x4){0.f, 0.f, 0.f, 0.f};

    BAR_VM0();  // Asw landed

    for (int cc = 0; cc < 8; cc++) {
        const int par = cc & 1;

        // ---- GEMM1 (swapped) over all k: acc1[kc][n2][t2] = H^T frags ----
        f32x4 acc1[KCNT][2][2];
#pragma unroll
        for (int kc = 0; kc < KCNT; kc++)
#pragma unroll
            for (int n2 = 0; n2 < 2; n2++)
#pragma unroll
                for (int t2 = 0; t2 < 2; t2++) acc1[kc][n2][t2] = (f32x4){0.f, 0.f, 0.f, 0.f};

        __builtin_amdgcn_s_setprio(1);
#pragma unroll
        for (int ks = 0; ks < 8; ks++) {
            bf16x8 w1f[2];
#pragma unroll
            for (int n2 = 0; n2 < 2; n2++) {
                int tile_n = cc * 8 + wn * 2 + n2;
                w1f[n2] = *(const bf16x8*)(W1frag + ((size_t)(tile_n * 8 + ks) * 64 + lane) * 8);
            }
            bf16x8 af[KCNT][2];
#pragma unroll
            for (int kc = 0; kc < KCNT; kc++)
#pragma unroll
                for (int t2 = 0; t2 < 2; t2++) {
                    int row = kc * 32 + t2 * 16 + (lane & 15);
                    af[kc][t2] = *(const bf16x8*)((const char*)Asw + row * 512 +
                                                  ((ks * 64 + (lane >> 4) * 16) ^ ((row & 7) << 4)));
                }
#pragma unroll
            for (int kc = 0; kc < KCNT; kc++)
#pragma unroll
                for (int n2 = 0; n2 < 2; n2++)
#pragma unroll
                    for (int t2 = 0; t2 < 2; t2++)
                        acc1[kc][n2][t2] = __builtin_amdgcn_mfma_f32_16x16x32_bf16(
                            w1f[n2], af[kc][t2], acc1[kc][n2][t2], 0, 0, 0);
        }
        __builtin_amdgcn_s_setprio(0);

        // ---- combine: Hsw[par][t][h] = sum_k wk*gelu(acc1 + b1) (bf16) ----
#pragma unroll
        for (int n2 = 0; n2 < 2; n2++) {
            const int hloc = wn * 32 + n2 * 16 + (lane >> 4) * 4;  // 4 consecutive h
            f32x4 bb = *(const f32x4*)(b1 + cc * 128 + hloc);
#pragma unroll
            for (int t2 = 0; t2 < 2; t2++) {
                float hc[4];
#pragma unroll
                for (int r = 0; r < 4; r++) {
                    float s = 0.0f;
#pragma unroll
                    for (int kc = 0; kc < KCNT; kc++)
                        s += wkv[kc] * gelu_fast(acc1[kc][n2][t2][r] + bb[r]);
                    hc[r] = s;
                }
                uint32_t lo, hi;
                asm("v_cvt_pk_bf16_f32 %0, %1, %2" : "=v"(lo) : "v"(hc[0]), "v"(hc[1]));
                asm("v_cvt_pk_bf16_f32 %0, %1, %2" : "=v"(hi) : "v"(hc[2]), "v"(hc[3]));
                uint2 pk;
                pk.x = lo;
                pk.y = hi;
                int t = t2 * 16 + (lane & 15);
                *(uint2*)((char*)&Hsw[par][0] + t * 256 +
                          ((hloc * 2) ^ ((t & 7) << 4))) = pk;
            }
        }
        BAR_LGKM();  // Hsw[par] visible; global prefetches stay in flight

        // ---- GEMM2 once per chunk: acc2 += Hcomb @ W2chunk ----
        __builtin_amdgcn_s_setprio(1);
#pragma unroll
        for (int ks2 = 0; ks2 < 4; ks2++) {
            bf16x8 af2[2], w2f[4];
#pragma unroll
            for (int t2 = 0; t2 < 2; t2++) {
                int row = t2 * 16 + (lane & 15);
                af2[t2] = *(const bf16x8*)((const char*)&Hsw[par][0] + row * 256 +
                                           ((ks2 * 64 + (lane >> 4) * 16) ^ ((row & 7) << 4)));
            }
#pragma unroll
            for (int nn = 0; nn < 4; nn++) {
                int tile_n = wn * 4 + nn;
                int tile_k = cc * 4 + ks2;
                w2f[nn] = *(const bf16x8*)(W2frag + ((size_t)(tile_n * 32 + tile_k) * 64 + lane) * 8);
            }
#pragma unroll
            for (int t2 = 0; t2 < 2; t2++)
#pragma unroll
                for (int nn = 0; nn < 4; nn++)
                    acc2[t2][nn] = __builtin_amdgcn_mfma_f32_16x16x32_bf16(af2[t2], w2f[nn],
                                                                           acc2[t2][nn], 0, 0, 0);
        }
        __builtin_amdgcn_s_setprio(0);
        // no barrier: next chunk writes Hsw[par^1], whose readers (GEMM2 at
        // cc-1) are ordered before the BAR_LGKM above.
    }

    // ---- epilogue: out = osrc + acc2 + b2scale*b2 ----
#pragma unroll
    for (int nn = 0; nn < 4; nn++) {
        int col = wn * 64 + nn * 16 + (lane & 15);
        float bb = b2scale * b2[col];
#pragma unroll
        for (int t2 = 0; t2 < 2; t2++) {
            int rbase = row0 + t2 * 16 + (lane >> 4) * 4;
#pragma unroll
            for (int r = 0; r < 4; r++) {
                size_t idx = (size_t)(rbase + r) * C_DIM + col;
                out[idx] = osrc[idx] + acc2[t2][nn][r] + bb;
            }
        }
    }
}

// ------------------------------------------------------------------
extern "C" void kernel_launch(void* const* d_in, const int* in_sizes, int n_in,
                              void* d_out, int out_size, void* d_ws, size_t ws_size,
                              hipStream_t stream) {
    const float* x  = (const float*)d_in[0];
    const float* Wc = (const float*)d_in[1];
    const float* bc = (const float*)d_in[2];
    const float* W1 = (const float*)d_in[3];
    const float* b1 = (const float*)d_in[4];
    const float* W2 = (const float*)d_in[5];
    const float* b2 = (const float*)d_in[6];
    float* out = (float*)d_out;

    const size_t CONV_ELEMS = (size_t)B_DIM * T_LEN * C_DIM;     // 8M
    const size_t CONV_BYTES = CONV_ELEMS * 2;                    // 16.78 MB
    const size_t MAGS_BYTES = (size_t)B_DIM * C_DIM * 2048 * 2;  // 8.39 MB (bf16)
    const size_t XT_BYTES = (size_t)B_DIM * T_LEN * C_DIM * 4;   // 33.55 MB

    // ---- fixed carve ----
    uint8_t* ws = (uint8_t*)d_ws;
    size_t off = 0;
    auto alloc = [&](size_t bytes) {
        size_t o = off;
        off = (off + bytes + 255) & ~(size_t)255;
        return o;
    };
    float* partial = (float*)(ws + alloc((size_t)B_DIM * 8 * 2048 * 4));
    int* meta_p = (int*)(ws + alloc(B_DIM * K_TOP * 4));
    float* meta_w = (float*)(ws + alloc(B_DIM * K_TOP * 4));
    unsigned short* xbf = (unsigned short*)(ws + alloc((size_t)B_DIM * T_LEN * C_DIM * 2));
    unsigned short* WcT = (unsigned short*)(ws + alloc((size_t)256 * 2304 * 2));
    unsigned short* W1frag = (unsigned short*)(ws + alloc((size_t)256 * 1024 * 2));
    unsigned short* W2frag = (unsigned short*)(ws + alloc((size_t)1024 * 256 * 2));
    unsigned short* zbuf = (unsigned short*)(ws + alloc(512));

    // ---- tiered regionA ----
    size_t remaining = (ws_size > off) ? (ws_size - off) : 0;
    uint8_t* regionA = ws + off;
    int tier;  // 2=FULL(4 convbufs), 1=MID(1 convbuf + xT), 0=MIN
    if (remaining >= 4 * CONV_BYTES) tier = 2;
    else if (remaining >= MAGS_BYTES + XT_BYTES) tier = 1;
    else tier = 0;

    unsigned short* mags = (unsigned short*)regionA;  // FFT phase (dead before conv)
    float* xT = (float*)(regionA + ((tier == 2) ? CONV_BYTES : MAGS_BYTES));
    unsigned short* convbufs = (unsigned short*)regionA;
    const int use_xT = (tier >= 1);

    // 1. x -> {xT, xbf, zbuf} in one read (fused); fallback: xbf only
    if (use_xT) {
        transpose_cvtx_kernel<<<dim3(T_LEN / 32, C_DIM / 32, B_DIM), 256, 0, stream>>>(
            x, xT, xbf, zbuf);
    } else {
        cvt_x_kernel<<<dim3((B_DIM * T_LEN * C_DIM / 4) / 256), 256, 0, stream>>>(
            (const float4*)x, (ushort4*)xbf, zbuf);
    }

    // 2. weight prep
    transpose_cvt_kernel<<<dim3(256 / 32, 2304 / 32), 256, 0, stream>>>(Wc, WcT, 2304, 256);
    repack_frag_kernel<<<dim3(128), 256, 0, stream>>>(W1, W1frag, 256, 1024);
    repack_frag_kernel<<<dim3(128), 256, 0, stream>>>(W2, W2frag, 1024, 256);

    // 3. FFT magnitudes (bf16), reduce, top-4
    if (use_xT) {
        fft_mag_kernel<<<dim3(B_DIM * C_DIM), 256, 0, stream>>>(xT, mags, 1);
    } else {
        fft_mag_kernel<<<dim3(B_DIM * C_DIM), 256, 0, stream>>>(x, mags, 0);
    }
    reduce_amps_kernel<<<dim3(2048 / 256, 8, B_DIM), 256, 0, stream>>>(mags, partial);
    topk_kernel<<<dim3(B_DIM), 256, 0, stream>>>(partial, meta_p, meta_w);

    // 4. conv (all k) then fused FF (combined over k)
    if (tier == 2) {
        conv_mfma_kernel<<<dim3(32, B_DIM, K_TOP), 512, 0, stream>>>(
            xbf, WcT, bc, meta_p, zbuf, convbufs, CONV_ELEMS, 0);
        fused_ff_kernel<4><<<dim3(B_DIM * T_LEN / 32), 256, 0, stream>>>(
            convbufs, CONV_ELEMS, W1frag, W2frag, b1, b2, meta_w, out, x, 1.0f, 0);
    } else {
        for (int k = 0; k < K_TOP; k++) {
            conv_mfma_kernel<<<dim3(32, B_DIM, 1), 512, 0, stream>>>(
                xbf, WcT, bc, meta_p, zbuf, convbufs, 0, k);
            fused_ff_kernel<1><<<dim3(B_DIM * T_LEN / 32), 256, 0, stream>>>(
                convbufs, 0, W1frag, W2frag, b1, b2, meta_w, out,
                (k == 0) ? x : out, (k == K_TOP - 1) ? 1.0f : 0.0f, k);
        }
    }
}

// Round 15
// 367.440 us; speedup vs baseline: 1.1030x; 1.0474x over previous
//
#include <hip/hip_runtime.h>
#include <cstdint>
#include <cstddef>

#define T_LEN 4096
#define C_DIM 256
#define B_DIM 8
#define K_TOP 4

typedef __attribute__((ext_vector_type(8))) short bf16x8;
typedef __attribute__((ext_vector_type(4))) float f32x4;

// tanh-form GELU: x * sigmoid(1.59577x + 0.0713548x^3); |delta| vs exact
// erf-GELU ~2.5e-4, below the bf16 quant noise already in the buffers.
__device__ __forceinline__ float gelu_fast(float x) {
    float x2 = x * x;
    float a = x * fmaf(0.071354816f, x2, 1.595769122f);
    float e = __expf(-a);
    return __fdividef(x, 1.0f + e);
}

__device__ __forceinline__ unsigned short f2bf(float f) {
    uint32_t u = __float_as_uint(f);
    uint32_t r = (u + 0x7fffu + ((u >> 16) & 1u)) >> 16;
    return (unsigned short)r;
}

__device__ __forceinline__ float bf2f(unsigned short v) {
    uint32_t u = ((uint32_t)v) << 16;
    return __uint_as_float(u);
}

typedef __attribute__((address_space(3))) uint32_t lds_u32_t;
typedef __attribute__((address_space(1))) const uint32_t gbl_u32_t;

__device__ __forceinline__ void lds_load16(const void* g, void* l) {
    __builtin_amdgcn_global_load_lds((gbl_u32_t*)g, (lds_u32_t*)l, 16, 0, 0);
}

// raw barriers with explicit (counted) waits
#define BAR_VM0()                                                      \
    do {                                                               \
        asm volatile("s_waitcnt vmcnt(0) lgkmcnt(0)" ::: "memory");    \
        __builtin_amdgcn_s_barrier();                                  \
        __builtin_amdgcn_sched_barrier(0);                             \
    } while (0)
#define BAR_VM3()                                                      \
    do {                                                               \
        asm volatile("s_waitcnt vmcnt(3) lgkmcnt(0)" ::: "memory");    \
        __builtin_amdgcn_s_barrier();                                  \
        __builtin_amdgcn_sched_barrier(0);                             \
    } while (0)
#define BAR_LGKM()                                                     \
    do {                                                               \
        asm volatile("s_waitcnt lgkmcnt(0)" ::: "memory");             \
        __builtin_amdgcn_s_barrier();                                  \
        __builtin_amdgcn_sched_barrier(0);                             \
    } while (0)

// padded LDS index for FFT: +1 float per 32
#define FPAD(i) ((i) + ((i) >> 5))

// ------------------------------------------------------------------
// Fallback (no-xT tier): xbf = bf16(x), plus zero page
// ------------------------------------------------------------------
__global__ __launch_bounds__(256) void cvt_x_kernel(const float4* __restrict__ x,
                                                    ushort4* __restrict__ xbf,
                                                    unsigned short* __restrict__ zbuf) {
    size_t i = (size_t)blockIdx.x * 256 + threadIdx.x;
    float4 v = x[i];
    ushort4 o;
    o.x = f2bf(v.x); o.y = f2bf(v.y); o.z = f2bf(v.z); o.w = f2bf(v.w);
    xbf[i] = o;
    if (blockIdx.x == 0 && threadIdx.x < 256) zbuf[threadIdx.x] = 0;
}

// ------------------------------------------------------------------
// Fused: one read of x produces xT[b][c][t] (BF16, for FFT) AND
// xbf[b][t][c] (bf16, for conv), plus the zero page.
// ------------------------------------------------------------------
__global__ __launch_bounds__(256) void transpose_cvtx_kernel(const float* __restrict__ x,
                                                             unsigned short* __restrict__ xTb,
                                                             unsigned short* __restrict__ xbf,
                                                             unsigned short* __restrict__ zbuf) {
    __shared__ float tile[32][33];
    const int b = blockIdx.z;
    const int t0 = blockIdx.x * 32, c0 = blockIdx.y * 32;
    const int lx = threadIdx.x & 31, ly = threadIdx.x >> 5;
    const float* xp = x + (size_t)b * T_LEN * C_DIM;
    unsigned short* xbp = xbf + (size_t)b * T_LEN * C_DIM;
    unsigned short* op = xTb + (size_t)b * C_DIM * T_LEN;
    for (int rr = ly; rr < 32; rr += 8) {
        float v = xp[(size_t)(t0 + rr) * C_DIM + c0 + lx];
        tile[rr][lx] = v;
        xbp[(size_t)(t0 + rr) * C_DIM + c0 + lx] = f2bf(v);
    }
    __syncthreads();
    for (int rr = ly; rr < 32; rr += 8)
        op[(size_t)(c0 + rr) * T_LEN + t0 + lx] = f2bf(tile[lx][rr]);
    if (blockIdx.x == 0 && blockIdx.y == 0 && blockIdx.z == 0)
        zbuf[threadIdx.x] = 0;
}

// ------------------------------------------------------------------
// fp32 src[K][N] -> bf16 MFMA fragment tiles (A- and B-compatible).
// ------------------------------------------------------------------
__global__ __launch_bounds__(256) void repack_frag_kernel(const float* __restrict__ src,
                                                          unsigned short* __restrict__ dst,
                                                          int K, int N) {
    int idx = blockIdx.x * 256 + threadIdx.x;  // (tile, lane)
    int total = (N >> 4) * (K >> 5) * 64;
    if (idx >= total) return;
    int lane = idx & 63, tile = idx >> 6;
    int ktiles = K >> 5;
    int tile_n = tile / ktiles, tile_k = tile % ktiles;
    int col = tile_n * 16 + (lane & 15);
    int k0 = tile_k * 32 + (lane >> 4) * 8;
    __align__(16) unsigned short v[8];
#pragma unroll
    for (int j = 0; j < 8; j++) v[j] = f2bf(src[(size_t)(k0 + j) * N + col]);
    *(uint4*)(dst + (size_t)idx * 8) = *(const uint4*)v;
}

// ------------------------------------------------------------------
// fp32 [R][C] -> bf16 transposed [C][R]   (conv weights)
// ------------------------------------------------------------------
__global__ __launch_bounds__(256) void transpose_cvt_kernel(const float* __restrict__ src,
                                                            unsigned short* __restrict__ dst,
                                                            int R, int C) {
    __shared__ float t[32][33];
    const int c0 = blockIdx.x * 32, r0 = blockIdx.y * 32;
    const int lx = threadIdx.x & 31, ly = threadIdx.x >> 5;
    for (int rr = ly; rr < 32; rr += 8) {
        int r = r0 + rr, c = c0 + lx;
        t[rr][lx] = (r < R && c < C) ? src[(size_t)r * C + c] : 0.0f;
    }
    __syncthreads();
    for (int rr = ly; rr < 32; rr += 8) {
        int c = c0 + rr, r = r0 + lx;
        if (r < R && c < C) dst[(size_t)c * R + r] = f2bf(t[lx][rr]);
    }
}

// ------------------------------------------------------------------
// 2-for-1 real FFT: one complex 4096-pt FFT per CHANNEL PAIR
// (re = channel 2c, im = channel 2c+1, from bf16 xT), then Hermitian
// separation:  X_c = (Z_f + conj(Z_{N-f}))/2,
//              X_{c+1} = (Z_f - conj(Z_{N-f}))/(2i).
// Fused radix-2 stage-pairs, pad-32 LDS.  Writes both bf16 mag rows.
// ------------------------------------------------------------------
__global__ __launch_bounds__(256) void fft_mag_pair_kernel(const unsigned short* __restrict__ xTb,
                                                           unsigned short* __restrict__ mags) {
    const int bx = blockIdx.x;
    const int b = bx >> 7;
    const int c0 = (bx & 127) * 2;
    const int tid = threadIdx.x;

    __shared__ __align__(16) float re[4224];
    __shared__ __align__(16) float im[4224];
    __shared__ __align__(16) float twr[2048];
    __shared__ __align__(16) float twi[2048];

    for (int u = tid; u < 2048; u += 256) {
        float ang = -6.283185307179586f * (float)u / 4096.0f;
        float s, co;
        sincosf(ang, &s, &co);
        twr[u] = co;
        twi[u] = s;
    }

    {
        const uint4* r0 = (const uint4*)(xTb + ((size_t)(b * C_DIM + c0)) * T_LEN);
        const uint4* r1 = (const uint4*)(xTb + ((size_t)(b * C_DIM + c0 + 1)) * T_LEN);
        for (int e8 = tid; e8 < 512; e8 += 256) {
            uint4 v0 = r0[e8], v1 = r1[e8];
            const unsigned short* p0 = (const unsigned short*)&v0;
            const unsigned short* p1 = (const unsigned short*)&v1;
            int e = e8 * 8;
#pragma unroll
            for (int j = 0; j < 8; j++) {
                int r = (int)(__brev((unsigned)(e + j)) >> 20);
                re[FPAD(r)] = bf2f(p0[j]);
                im[FPAD(r)] = bf2f(p1[j]);
            }
        }
    }
    __syncthreads();

#pragma unroll
    for (int sp = 0; sp < 6; sp++) {
        const int h = 1 << (2 * sp);
        const int t1s = 11 - 2 * sp;
        const int t2s = 10 - 2 * sp;
        for (int j = tid; j < 1024; j += 256) {
            int p = j & (h - 1);
            int G = j >> (2 * sp);
            int base = G * 4 * h + p;
            int iA = FPAD(base), iB = FPAD(base + h);
            int iC = FPAD(base + 2 * h), iD = FPAD(base + 3 * h);
            float w1r = twr[p << t1s], w1i = twi[p << t1s];
            float w2r = twr[p << t2s], w2i = twi[p << t2s];
            float Ar = re[iA], Ai = im[iA], Br = re[iB], Bi = im[iB];
            float Cr = re[iC], Ci = im[iC], Dr = re[iD], Di = im[iD];
            float tBr = w1r * Br - w1i * Bi, tBi = w1r * Bi + w1i * Br;
            float tDr = w1r * Dr - w1i * Di, tDi = w1r * Di + w1i * Dr;
            float A1r = Ar + tBr, A1i = Ai + tBi;
            float B1r = Ar - tBr, B1i = Ai - tBi;
            float C1r = Cr + tDr, C1i = Ci + tDi;
            float D1r = Cr - tDr, D1i = Ci - tDi;
            float tCr = w2r * C1r - w2i * C1i, tCi = w2r * C1i + w2i * C1r;
            float uDr = w2r * D1r - w2i * D1i, uDi = w2r * D1i + w2i * D1r;
            float vDr = uDi, vDi = -uDr;
            re[iA] = A1r + tCr; im[iA] = A1i + tCi;
            re[iC] = A1r - tCr; im[iC] = A1i - tCi;
            re[iB] = B1r + vDr; im[iB] = B1i + vDi;
            re[iD] = B1r - vDr; im[iD] = B1i - vDi;
        }
        __syncthreads();
    }

    unsigned short* mp0 = mags + ((size_t)(b * C_DIM + c0)) * 2048;
    unsigned short* mp1 = mp0 + 2048;
    for (int u = tid; u < 2048; u += 256) {
        int f = u + 1;
        int g = 4096 - f;
        int jf = FPAD(f), jg = FPAD(g);
        float ar = re[jf], ai = im[jf];
        float br = re[jg], bi = im[jg];
        float xr = ar + br, xi = ai - bi;  // 2*X_c
        float yr = ai + bi, yi = br - ar;  // 2*X_{c+1}
        mp0[u] = f2bf(0.5f * sqrtf(xr * xr + xi * xi));
        mp1[u] = f2bf(0.5f * sqrtf(yr * yr + yi * yi));
    }
}

// ------------------------------------------------------------------
// Fallback per-channel FFT (strided fp32 x input), bf16 mags out.
// ------------------------------------------------------------------
__global__ __launch_bounds__(256) void fft_mag_kernel(const float* __restrict__ src,
                                                      unsigned short* __restrict__ mags) {
    const int bx = blockIdx.x;
    const int b = bx >> 8;
    const int c = bx & 255;
    const int tid = threadIdx.x;

    __shared__ __align__(16) float re[4224];
    __shared__ __align__(16) float im[4224];
    __shared__ __align__(16) float twr[2048];
    __shared__ __align__(16) float twi[2048];

    for (int u = tid; u < 2048; u += 256) {
        float ang = -6.283185307179586f * (float)u / 4096.0f;
        float s, co;
        sincosf(ang, &s, &co);
        twr[u] = co;
        twi[u] = s;
    }
    for (int i = tid; i < 4224; i += 256) im[i] = 0.0f;

    const float* xp = src + (size_t)b * T_LEN * C_DIM + c;
    for (int e = tid; e < 4096; e += 256) {
        int r = (int)(__brev((unsigned)e) >> 20);
        re[FPAD(r)] = xp[(size_t)e * C_DIM];
    }
    __syncthreads();

#pragma unroll
    for (int sp = 0; sp < 6; sp++) {
        const int h = 1 << (2 * sp);
        const int t1s = 11 - 2 * sp;
        const int t2s = 10 - 2 * sp;
        for (int j = tid; j < 1024; j += 256) {
            int p = j & (h - 1);
            int G = j >> (2 * sp);
            int base = G * 4 * h + p;
            int iA = FPAD(base), iB = FPAD(base + h);
            int iC = FPAD(base + 2 * h), iD = FPAD(base + 3 * h);
            float w1r = twr[p << t1s], w1i = twi[p << t1s];
            float w2r = twr[p << t2s], w2i = twi[p << t2s];
            float Ar = re[iA], Ai = im[iA], Br = re[iB], Bi = im[iB];
            float Cr = re[iC], Ci = im[iC], Dr = re[iD], Di = im[iD];
            float tBr = w1r * Br - w1i * Bi, tBi = w1r * Bi + w1i * Br;
            float tDr = w1r * Dr - w1i * Di, tDi = w1r * Di + w1i * Dr;
            float A1r = Ar + tBr, A1i = Ai + tBi;
            float B1r = Ar - tBr, B1i = Ai - tBi;
            float C1r = Cr + tDr, C1i = Ci + tDi;
            float D1r = Cr - tDr, D1i = Ci - tDi;
            float tCr = w2r * C1r - w2i * C1i, tCi = w2r * C1i + w2i * C1r;
            float uDr = w2r * D1r - w2i * D1i, uDi = w2r * D1i + w2i * D1r;
            float vDr = uDi, vDi = -uDr;
            re[iA] = A1r + tCr; im[iA] = A1i + tCi;
            re[iC] = A1r - tCr; im[iC] = A1i - tCi;
            re[iB] = B1r + vDr; im[iB] = B1i + vDi;
            re[iD] = B1r - vDr; im[iD] = B1i - vDi;
        }
        __syncthreads();
    }

    unsigned short* mp = mags + ((size_t)(b * C_DIM + c)) * 2048;
    for (int u = tid; u < 2048; u += 256) {
        int f = FPAD(u + 1);
        mp[u] = f2bf(sqrtf(re[f] * re[f] + im[f] * im[f]));
    }
}

// ------------------------------------------------------------------
// partial[b][cc][u] = sum over 32 channels of mags (bf16 in, fp32 out)
// ------------------------------------------------------------------
__global__ __launch_bounds__(256) void reduce_amps_kernel(const unsigned short* __restrict__ mags,
                                                          float* __restrict__ partial) {
    const int b = blockIdx.z, cc = blockIdx.y;
    const int u = blockIdx.x * 256 + threadIdx.x;
    const unsigned short* mp = mags + ((size_t)b * C_DIM + cc * 32) * 2048 + u;
    float s = 0.0f;
    for (int c = 0; c < 32; c++) s += bf2f(mp[(size_t)c * 2048]);
    partial[((size_t)b * 8 + cc) * 2048 + u] = s;
}

// ------------------------------------------------------------------
// Per-batch top-4 (value desc, ties -> lower index), periods, softmax
// ------------------------------------------------------------------
__global__ __launch_bounds__(256) void topk_kernel(const float* __restrict__ partial,
                                                   int* __restrict__ meta_p,
                                                   float* __restrict__ meta_w) {
    const int b = blockIdx.x;
    const int tid = threadIdx.x;
    __shared__ float v[2048];
    __shared__ float rv[256];
    __shared__ int ri[256];
    __shared__ float topv[K_TOP];
    __shared__ int topi[K_TOP];

    for (int u = tid; u < 2048; u += 256) {
        float s = 0.0f;
        for (int cc = 0; cc < 8; cc++) s += partial[((size_t)b * 8 + cc) * 2048 + u];
        v[u] = s * (1.0f / (float)C_DIM);
    }

    for (int k = 0; k < K_TOP; k++) {
        __syncthreads();
        float bv = -1e30f;
        int bi = 2048;
        for (int u = tid; u < 2048; u += 256) {
            float val = v[u];
            if (val > bv) { bv = val; bi = u; }
        }
        rv[tid] = bv;
        ri[tid] = bi;
        __syncthreads();
        for (int s = 128; s > 0; s >>= 1) {
            if (tid < s) {
                float ov = rv[tid + s];
                int oi = ri[tid + s];
                if (ov > rv[tid] || (ov == rv[tid] && oi < ri[tid])) {
                    rv[tid] = ov;
                    ri[tid] = oi;
                }
            }
            __syncthreads();
        }
        if (tid == 0) {
            topv[k] = rv[0];
            topi[k] = ri[0];
            v[ri[0]] = -1e30f;
        }
    }
    __syncthreads();
    if (tid == 0) {
        float mx = topv[0];
        for (int k = 1; k < K_TOP; k++) mx = fmaxf(mx, topv[k]);
        float e[K_TOP], se = 0.0f;
        for (int k = 0; k < K_TOP; k++) { e[k] = expf(topv[k] - mx); se += e[k]; }
        for (int k = 0; k < K_TOP; k++) {
            int idx = topi[k];
            int d = (idx >= 1) ? idx : 1;
            int p = T_LEN / d;
            if (p < 1) p = 1;
            meta_p[b * K_TOP + k] = p;
            meta_w[b * K_TOP + k] = e[k] / se;
        }
    }
}

// ------------------------------------------------------------------
// Conv as MFMA GEMM (round-14 version, measured 175us): 128x256 tile,
// 512 thr / 8 waves (wave tile 64x64), 3-buffer LDS pipeline (stage
// s+2 while computing s), counted vmcnt(3) barriers, zero-conflict
// swizzle key (row>>1)&3, setprio, gelu_fast.  72 KB -> 2 blocks/CU.
// ------------------------------------------------------------------
__global__ __launch_bounds__(512) void conv_mfma_kernel(const unsigned short* __restrict__ xbf,
                                                        const unsigned short* __restrict__ WcT,
                                                        const float* __restrict__ bc,
                                                        const int* __restrict__ meta_p,
                                                        const unsigned short* __restrict__ zbuf,
                                                        unsigned short* __restrict__ convbufs,
                                                        size_t conv_stride, int koff) {
    const int b = blockIdx.y;
    const int kz = blockIdx.z;
    const int n = meta_p[b * K_TOP + koff + kz];
    const int row0 = blockIdx.x * 128;
    const int tid = threadIdx.x, w = tid >> 6, lane = tid & 63;
    const int wm = w >> 2, wn = w & 3;

    __shared__ __align__(16) unsigned short Al[3][128 * 32];
    __shared__ __align__(16) unsigned short Bl[3][256 * 32];

    const int ra = tid >> 2;
    const int swz = ((tid & 3) ^ ((ra >> 1) & 3)) * 8;
    int ti, tj;
    {
        int t = row0 + ra;
        ti = t / n;
        tj = t - ti * n;
    }
    const unsigned short* xb = xbf + (size_t)b * T_LEN * C_DIM;
    const unsigned short* baseB0 = WcT + (size_t)ra * 2304 + swz;
    const unsigned short* baseB1 = WcT + (size_t)(ra + 128) * 2304 + swz;

    auto computeA = [&](int q) -> const unsigned short* {
        int di = q / 3 - 1, dj = q % 3 - 1;
        int ii = ti + di, jj = tj + dj;
        int tp = ii * n + jj;
        bool ok = (jj >= 0) && (jj < n) && (ii >= 0) && (tp < T_LEN);
        return ok ? (xb + (size_t)tp * C_DIM + swz) : (zbuf + swz);
    };

    f32x4 acc[4][4];
#pragma unroll
    for (int m = 0; m < 4; m++)
#pragma unroll
        for (int nn = 0; nn < 4; nn++) acc[m][nn] = (f32x4){0.f, 0.f, 0.f, 0.f};

    const unsigned short* baseA = computeA(0);
    lds_load16(baseA, &Al[0][tid * 8]);
    lds_load16(baseB0, &Bl[0][tid * 8]);
    lds_load16(baseB1, &Bl[0][4096 + tid * 8]);
    lds_load16(baseA + 32, &Al[1][tid * 8]);
    lds_load16(baseB0 + 32, &Bl[1][tid * 8]);
    lds_load16(baseB1 + 32, &Bl[1][4096 + tid * 8]);

    int cur = 0, stb = 2;
    for (int s = 0; s < 72; s++) {
        if (s < 71) BAR_VM3();
        else        BAR_VM0();

        const int t = s + 2;
        if (t < 72) {
            if ((t & 7) == 0) baseA = computeA(t >> 3);
            lds_load16(baseA + (t & 7) * 32, &Al[stb][tid * 8]);
            lds_load16(baseB0 + (size_t)t * 32, &Bl[stb][tid * 8]);
            lds_load16(baseB1 + (size_t)t * 32, &Bl[stb][4096 + tid * 8]);
        }

        bf16x8 af[4], bfr[4];
#pragma unroll
        for (int m = 0; m < 4; m++) {
            int row = wm * 64 + m * 16 + (lane & 15);
            af[m] = *(const bf16x8*)((const char*)&Al[cur][0] + row * 64 +
                                     (((lane >> 4) * 16) ^ (((row >> 1) & 3) << 4)));
        }
#pragma unroll
        for (int nn = 0; nn < 4; nn++) {
            int rowb = wn * 64 + nn * 16 + (lane & 15);
            bfr[nn] = *(const bf16x8*)((const char*)&Bl[cur][0] + rowb * 64 +
                                       (((lane >> 4) * 16) ^ (((rowb >> 1) & 3) << 4)));
        }
        __builtin_amdgcn_s_setprio(1);
#pragma unroll
        for (int m = 0; m < 4; m++)
#pragma unroll
            for (int nn = 0; nn < 4; nn++)
                acc[m][nn] = __builtin_amdgcn_mfma_f32_16x16x32_bf16(af[m], bfr[nn], acc[m][nn], 0, 0, 0);
        __builtin_amdgcn_s_setprio(0);

        cur = (cur == 2) ? 0 : cur + 1;
        stb = (stb == 2) ? 0 : stb + 1;
    }

    unsigned short* ob = convbufs + (size_t)kz * conv_stride + (size_t)b * T_LEN * C_DIM;
#pragma unroll
    for (int nn = 0; nn < 4; nn++) {
        int col = wn * 64 + nn * 16 + (lane & 15);
        float bs = bc[col];
#pragma unroll
        for (int m = 0; m < 4; m++) {
            int rbase = row0 + wm * 64 + m * 16 + (lane >> 4) * 4;
#pragma unroll
            for (int r = 0; r < 4; r++) {
                float v = acc[m][nn][r] + bs;
                ob[(size_t)(rbase + r) * C_DIM + col] = f2bf(gelu_fast(v));
            }
        }
    }
}

// ------------------------------------------------------------------
// Fused FF v5 (round-11, unchanged):
// out = osrc + (sum_k wk*gelu(A_k@W1+b1)) @ W2 + b2scale*b2
// ------------------------------------------------------------------
template <int KCNT>
__global__ __launch_bounds__(256, 2) void fused_ff_kernel(
    const unsigned short* __restrict__ convbufs, size_t conv_stride,
    const unsigned short* __restrict__ W1frag,
    const unsigned short* __restrict__ W2frag,
    const float* __restrict__ b1,
    const float* __restrict__ b2,
    const float* __restrict__ meta_w,
    float* __restrict__ out,
    const float* __restrict__ osrc,   // x (init) or out (accumulate)
    float b2scale, int koff) {
    const int tid = threadIdx.x;
    const int wn = tid >> 6, lane = tid & 63;
    const int row0 = blockIdx.x * 32;
    const int b = row0 >> 12;

    __shared__ __align__(16) unsigned short Asw[KCNT * 32 * 256];   // KCNT*16 KB
    __shared__ __align__(16) unsigned short Hsw[2][32 * 128];       // 2 x 8 KB

    float wkv[KCNT];
#pragma unroll
    for (int kc = 0; kc < KCNT; kc++) wkv[kc] = meta_w[b * K_TOP + koff + kc];

    // ---- stage all KCNT A-strips once (linear LDS dest, inv-swizzled src) ----
    {
        const unsigned short* base = convbufs + (size_t)row0 * C_DIM;
#pragma unroll
        for (int u = 0; u < KCNT * 4; u++) {
            int ch = u * 256 + tid;      // 16B chunk id
            int rfull = ch >> 5;         // row in Asw (= kc*32 + trow)
            int kc = rfull >> 5;
            int trow = rfull & 31;
            int cole = ((ch & 31) * 8) ^ ((rfull & 7) << 3);
            lds_load16(base + (size_t)kc * conv_stride + (size_t)trow * 256 + cole,
                       (unsigned short*)Asw + (size_t)ch * 8);
        }
    }

    f32x4 acc2[2][4];
#pragma unroll
    for (int t2 = 0; t2 < 2; t2++)
#pragma unroll
        for (int nn = 0; nn < 4; nn++) acc2[t2][nn] = (f32x4){0.f, 0.f, 0.f, 0.f};

    BAR_VM0();  // Asw landed

    for (int cc = 0; cc < 8; cc++) {
        const int par = cc & 1;

        // ---- GEMM1 (swapped) over all k: acc1[kc][n2][t2] = H^T frags ----
        f32x4 acc1[KCNT][2][2];
#pragma unroll
        for (int kc = 0; kc < KCNT; kc++)
#pragma unroll
            for (int n2 = 0; n2 < 2; n2++)
#pragma unroll
                for (int t2 = 0; t2 < 2; t2++) acc1[kc][n2][t2] = (f32x4){0.f, 0.f, 0.f, 0.f};

        __builtin_amdgcn_s_setprio(1);
#pragma unroll
        for (int ks = 0; ks < 8; ks++) {
            bf16x8 w1f[2];
#pragma unroll
            for (int n2 = 0; n2 < 2; n2++) {
                int tile_n = cc * 8 + wn * 2 + n2;
                w1f[n2] = *(const bf16x8*)(W1frag + ((size_t)(tile_n * 8 + ks) * 64 + lane) * 8);
            }
            bf16x8 af[KCNT][2];
#pragma unroll
            for (int kc = 0; kc < KCNT; kc++)
#pragma unroll
                for (int t2 = 0; t2 < 2; t2++) {
                    int row = kc * 32 + t2 * 16 + (lane & 15);
                    af[kc][t2] = *(const bf16x8*)((const char*)Asw + row * 512 +
                                                  ((ks * 64 + (lane >> 4) * 16) ^ ((row & 7) << 4)));
                }
#pragma unroll
            for (int kc = 0; kc < KCNT; kc++)
#pragma unroll
                for (int n2 = 0; n2 < 2; n2++)
#pragma unroll
                    for (int t2 = 0; t2 < 2; t2++)
                        acc1[kc][n2][t2] = __builtin_amdgcn_mfma_f32_16x16x32_bf16(
                            w1f[n2], af[kc][t2], acc1[kc][n2][t2], 0, 0, 0);
        }
        __builtin_amdgcn_s_setprio(0);

        // ---- combine: Hsw[par][t][h] = sum_k wk*gelu(acc1 + b1) (bf16) ----
#pragma unroll
        for (int n2 = 0; n2 < 2; n2++) {
            const int hloc = wn * 32 + n2 * 16 + (lane >> 4) * 4;  // 4 consecutive h
            f32x4 bb = *(const f32x4*)(b1 + cc * 128 + hloc);
#pragma unroll
            for (int t2 = 0; t2 < 2; t2++) {
                float hc[4];
#pragma unroll
                for (int r = 0; r < 4; r++) {
                    float s = 0.0f;
#pragma unroll
                    for (int kc = 0; kc < KCNT; kc++)
                        s += wkv[kc] * gelu_fast(acc1[kc][n2][t2][r] + bb[r]);
                    hc[r] = s;
                }
                uint32_t lo, hi;
                asm("v_cvt_pk_bf16_f32 %0, %1, %2" : "=v"(lo) : "v"(hc[0]), "v"(hc[1]));
                asm("v_cvt_pk_bf16_f32 %0, %1, %2" : "=v"(hi) : "v"(hc[2]), "v"(hc[3]));
                uint2 pk;
                pk.x = lo;
                pk.y = hi;
                int t = t2 * 16 + (lane & 15);
                *(uint2*)((char*)&Hsw[par][0] + t * 256 +
                          ((hloc * 2) ^ ((t & 7) << 4))) = pk;
            }
        }
        BAR_LGKM();  // Hsw[par] visible; global prefetches stay in flight

        // ---- GEMM2 once per chunk: acc2 += Hcomb @ W2chunk ----
        __builtin_amdgcn_s_setprio(1);
#pragma unroll
        for (int ks2 = 0; ks2 < 4; ks2++) {
            bf16x8 af2[2], w2f[4];
#pragma unroll
            for (int t2 = 0; t2 < 2; t2++) {
                int row = t2 * 16 + (lane & 15);
                af2[t2] = *(const bf16x8*)((const char*)&Hsw[par][0] + row * 256 +
                                           ((ks2 * 64 + (lane >> 4) * 16) ^ ((row & 7) << 4)));
            }
#pragma unroll
            for (int nn = 0; nn < 4; nn++) {
                int tile_n = wn * 4 + nn;
                int tile_k = cc * 4 + ks2;
                w2f[nn] = *(const bf16x8*)(W2frag + ((size_t)(tile_n * 32 + tile_k) * 64 + lane) * 8);
            }
#pragma unroll
            for (int t2 = 0; t2 < 2; t2++)
#pragma unroll
                for (int nn = 0; nn < 4; nn++)
                    acc2[t2][nn] = __builtin_amdgcn_mfma_f32_16x16x32_bf16(af2[t2], w2f[nn],
                                                                           acc2[t2][nn], 0, 0, 0);
        }
        __builtin_amdgcn_s_setprio(0);
        // no barrier: next chunk writes Hsw[par^1], whose readers (GEMM2 at
        // cc-1) are ordered before the BAR_LGKM above.
    }

    // ---- epilogue: out = osrc + acc2 + b2scale*b2 ----
#pragma unroll
    for (int nn = 0; nn < 4; nn++) {
        int col = wn * 64 + nn * 16 + (lane & 15);
        float bb = b2scale * b2[col];
#pragma unroll
        for (int t2 = 0; t2 < 2; t2++) {
            int rbase = row0 + t2 * 16 + (lane >> 4) * 4;
#pragma unroll
            for (int r = 0; r < 4; r++) {
                size_t idx = (size_t)(rbase + r) * C_DIM + col;
                out[idx] = osrc[idx] + acc2[t2][nn][r] + bb;
            }
        }
    }
}

// ------------------------------------------------------------------
extern "C" void kernel_launch(void* const* d_in, const int* in_sizes, int n_in,
                              void* d_out, int out_size, void* d_ws, size_t ws_size,
                              hipStream_t stream) {
    const float* x  = (const float*)d_in[0];
    const float* Wc = (const float*)d_in[1];
    const float* bc = (const float*)d_in[2];
    const float* W1 = (const float*)d_in[3];
    const float* b1 = (const float*)d_in[4];
    const float* W2 = (const float*)d_in[5];
    const float* b2 = (const float*)d_in[6];
    float* out = (float*)d_out;

    const size_t CONV_ELEMS = (size_t)B_DIM * T_LEN * C_DIM;     // 8M
    const size_t CONV_BYTES = CONV_ELEMS * 2;                    // 16.78 MB
    const size_t MAGS_BYTES = (size_t)B_DIM * C_DIM * 2048 * 2;  // 8.39 MB (bf16)
    const size_t XT_BYTES = (size_t)B_DIM * T_LEN * C_DIM * 2;   // 16.78 MB (bf16)

    // ---- fixed carve ----
    uint8_t* ws = (uint8_t*)d_ws;
    size_t off = 0;
    auto alloc = [&](size_t bytes) {
        size_t o = off;
        off = (off + bytes + 255) & ~(size_t)255;
        return o;
    };
    float* partial = (float*)(ws + alloc((size_t)B_DIM * 8 * 2048 * 4));
    int* meta_p = (int*)(ws + alloc(B_DIM * K_TOP * 4));
    float* meta_w = (float*)(ws + alloc(B_DIM * K_TOP * 4));
    unsigned short* xbf = (unsigned short*)(ws + alloc((size_t)B_DIM * T_LEN * C_DIM * 2));
    unsigned short* WcT = (unsigned short*)(ws + alloc((size_t)256 * 2304 * 2));
    unsigned short* W1frag = (unsigned short*)(ws + alloc((size_t)256 * 1024 * 2));
    unsigned short* W2frag = (unsigned short*)(ws + alloc((size_t)1024 * 256 * 2));
    unsigned short* zbuf = (unsigned short*)(ws + alloc(512));

    // ---- tiered regionA ----
    size_t remaining = (ws_size > off) ? (ws_size - off) : 0;
    uint8_t* regionA = ws + off;
    int tier;  // 2=FULL(4 convbufs), 1=MID(1 convbuf + xT), 0=MIN
    if (remaining >= 4 * CONV_BYTES) tier = 2;
    else if (remaining >= MAGS_BYTES + XT_BYTES) tier = 1;
    else tier = 0;

    unsigned short* mags = (unsigned short*)regionA;  // FFT phase (dead before conv)
    unsigned short* xTb = (unsigned short*)(regionA + ((tier == 2) ? CONV_BYTES : MAGS_BYTES));
    unsigned short* convbufs = (unsigned short*)regionA;
    const int use_xT = (tier >= 1);

    // 1. x -> {xTb, xbf, zbuf} in one read (fused); fallback: xbf only
    if (use_xT) {
        transpose_cvtx_kernel<<<dim3(T_LEN / 32, C_DIM / 32, B_DIM), 256, 0, stream>>>(
            x, xTb, xbf, zbuf);
    } else {
        cvt_x_kernel<<<dim3((B_DIM * T_LEN * C_DIM / 4) / 256), 256, 0, stream>>>(
            (const float4*)x, (ushort4*)xbf, zbuf);
    }

    // 2. weight prep
    transpose_cvt_kernel<<<dim3(256 / 32, 2304 / 32), 256, 0, stream>>>(Wc, WcT, 2304, 256);
    repack_frag_kernel<<<dim3(128), 256, 0, stream>>>(W1, W1frag, 256, 1024);
    repack_frag_kernel<<<dim3(128), 256, 0, stream>>>(W2, W2frag, 1024, 256);

    // 3. FFT magnitudes (2-for-1 paired when xT available), reduce, top-4
    if (use_xT) {
        fft_mag_pair_kernel<<<dim3(B_DIM * 128), 256, 0, stream>>>(xTb, mags);
    } else {
        fft_mag_kernel<<<dim3(B_DIM * C_DIM), 256, 0, stream>>>(x, mags);
    }
    reduce_amps_kernel<<<dim3(2048 / 256, 8, B_DIM), 256, 0, stream>>>(mags, partial);
    topk_kernel<<<dim3(B_DIM), 256, 0, stream>>>(partial, meta_p, meta_w);

    // 4. conv (all k) then fused FF (combined over k)
    if (tier == 2) {
        conv_mfma_kernel<<<dim3(32, B_DIM, K_TOP), 512, 0, stream>>>(
            xbf, WcT, bc, meta_p, zbuf, convbufs, CONV_ELEMS, 0);
        fused_ff_kernel<4><<<dim3(B_DIM * T_LEN / 32), 256, 0, stream>>>(
            convbufs, CONV_ELEMS, W1frag, W2frag, b1, b2, meta_w, out, x, 1.0f, 0);
    } else {
        for (int k = 0; k < K_TOP; k++) {
            conv_mfma_kernel<<<dim3(32, B_DIM, 1), 512, 0, stream>>>(
                xbf, WcT, bc, meta_p, zbuf, convbufs, 0, k);
            fused_ff_kernel<1><<<dim3(B_DIM * T_LEN / 32), 256, 0, stream>>>(
                convbufs, 0, W1frag, W2frag, b1, b2, meta_w, out,
                (k == 0) ? x : out, (k == K_TOP - 1) ? 1.0f : 0.0f, k);
        }
    }
}